// Round 4
// baseline (472.233 us; speedup 1.0000x reference)
//
#include <hip/hip_runtime.h>
#include <hip/hip_bf16.h>
#include <math.h>

// Problem constants (from reference)
#define B_   2
#define T_   2048
#define C_   1024
#define H_   8
#define KV_  4
#define D_   128
#define WIN_ 512
#define HID_ 4096
#define NTOK (B_*T_)          // 4096 tokens
#define QK_SCALE 0.08838834764831845f   // rsqrt(128)

typedef __bf16 bf16;
typedef __attribute__((ext_vector_type(8))) __bf16 bf16x8;   // MFMA A/B frag (4 VGPR)
typedef __attribute__((ext_vector_type(4))) __bf16 bf16x4;
typedef __attribute__((ext_vector_type(4))) float  f32x4;    // MFMA C/D frag

#define AS1 __attribute__((address_space(1)))
#define AS3 __attribute__((address_space(3)))

// async global->LDS, 16B/lane. LDS dest is wave-uniform base + lane*16 (m97 pattern).
__device__ __forceinline__ void gload_lds16(const bf16* g, bf16* l) {
  __builtin_amdgcn_global_load_lds((const AS1 void*)g, (AS3 void*)l, 16, 0, 0);
}

// ---------------------------------------------------------------------------
// Weight cast+transpose: dst[n][k] = (bf16)src[k][n].  B^T layout so GEMM
// B-fragments are 8-contiguous-k b128 reads (layout proven by m92/m97).
// grid: (N/32, K/32), block (32,8)
// ---------------------------------------------------------------------------
__global__ void transpose_cast_kernel(const float* __restrict__ src, int ldsrc,
                                      bf16* __restrict__ dst, int lddst,
                                      int K, int N) {
  __shared__ float tile[32][33];
  const int n0 = blockIdx.x * 32, k0 = blockIdx.y * 32;
  const int tx = threadIdx.x, ty = threadIdx.y;
#pragma unroll
  for (int i = 0; i < 32; i += 8)
    tile[ty + i][tx] = src[(size_t)(k0 + ty + i) * ldsrc + n0 + tx];
  __syncthreads();
#pragma unroll
  for (int i = 0; i < 32; i += 8)
    dst[(size_t)(n0 + ty + i) * lddst + k0 + tx] = (bf16)tile[tx][ty + i];
}

// V transpose: vt[(b*KV+h)*D + d][t] = qkv[b*T+t][1536 + h*128 + d]
// grid: (T/32, D/32, B*KV), block (32,8)
__global__ void transpose_v_kernel(const bf16* __restrict__ qkv, bf16* __restrict__ vt) {
  __shared__ bf16 tile[32][33];
  const int bh = blockIdx.z, b = bh >> 2, h = bh & 3;
  const int t0 = blockIdx.x * 32, d0 = blockIdx.y * 32;
  const int tx = threadIdx.x, ty = threadIdx.y;
#pragma unroll
  for (int i = 0; i < 32; i += 8)
    tile[ty + i][tx] = qkv[(size_t)(b * T_ + t0 + ty + i) * 2048 + 1536 + h * 128 + d0 + tx];
  __syncthreads();
#pragma unroll
  for (int i = 0; i < 32; i += 8)
    vt[(size_t)((b * KV_ + h) * D_ + d0 + ty + i) * T_ + t0 + tx] = tile[tx][ty + i];
}

// ---------------------------------------------------------------------------
// RoPE sin/cos table: [T][64] each (the two D/2 halves share angles)
// ---------------------------------------------------------------------------
__global__ void rope_table_kernel(float* __restrict__ ct, float* __restrict__ st) {
  const int idx = blockIdx.x * 256 + threadIdx.x;
  if (idx >= T_ * 64) return;
  const int t = idx >> 6, i = idx & 63;
  const float inv = __expf(-(float)i * (1.0f / 64.0f) * logf(10000.0f));
  const float a = (float)t * inv;
  ct[idx] = cosf(a);
  st[idx] = sinf(a);
}

// ---------------------------------------------------------------------------
// RMSNorm (fp32 in) -> bf16 out.  One block per row, 256 threads * float4.
// ---------------------------------------------------------------------------
__global__ __launch_bounds__(256) void rmsnorm_kernel(const float* __restrict__ x,
                                                      const float* __restrict__ scale,
                                                      bf16* __restrict__ out) {
  const int row = blockIdx.x;
  const float* xr = x + (size_t)row * C_;
  const int tid = threadIdx.x;
  float4 v = ((const float4*)xr)[tid];
  float ss = v.x * v.x + v.y * v.y + v.z * v.z + v.w * v.w;
#pragma unroll
  for (int o = 32; o > 0; o >>= 1) ss += __shfl_down(ss, o);
  __shared__ float part[4];
  __shared__ float total;
  if ((tid & 63) == 0) part[tid >> 6] = ss;
  __syncthreads();
  if (tid == 0) total = part[0] + part[1] + part[2] + part[3];
  __syncthreads();
  const float r = rsqrtf(total * (1.0f / C_) + 1e-6f);
  float4 sc = ((const float4*)scale)[tid];
  bf16x4 o4;
  o4[0] = (bf16)(v.x * r * (1.f + sc.x));
  o4[1] = (bf16)(v.y * r * (1.f + sc.y));
  o4[2] = (bf16)(v.z * r * (1.f + sc.z));
  o4[3] = (bf16)(v.w * r * (1.f + sc.w));
  *(bf16x4*)(out + (size_t)row * C_ + tid * 4) = o4;
}

// ---------------------------------------------------------------------------
// RoPE apply + scatter into attention layouts.
// qkv row layout: cols [0,1024) q heads (hh = r*KV+h), [1024,1536) k, rest v.
// Qr[b][hh][t][d] (scaled by rsqrt(D)), Kr[b][h][t][d].  V handled separately.
// grid: NTOK blocks, 256 threads (4 waves x 3 head-chunks, lane = rope pair idx)
// ---------------------------------------------------------------------------
__global__ __launch_bounds__(256) void rope_apply_kernel(const bf16* __restrict__ qkv,
                                                         const float* __restrict__ ct,
                                                         const float* __restrict__ st,
                                                         bf16* __restrict__ Qr,
                                                         bf16* __restrict__ Kr) {
  const int row = blockIdx.x;            // b*T + t
  const int b = row >> 11, t = row & (T_ - 1);
  const int w = threadIdx.x >> 6, lane = threadIdx.x & 63;
  const float c = ct[t * 64 + lane], s = st[t * 64 + lane];
#pragma unroll
  for (int q = 0; q < 3; ++q) {
    const int ch = w * 3 + q;            // 0..11  (8 q-heads, 4 k-heads)
    const bf16* src = qkv + (size_t)row * 2048 + ch * 128;
    float x1 = (float)src[lane], x2 = (float)src[lane + 64];
    float o1 = x1 * c - x2 * s;
    float o2 = x2 * c + x1 * s;
    bf16* dst;
    if (ch < 8) {
      o1 *= QK_SCALE; o2 *= QK_SCALE;
      dst = Qr + (size_t)((b * H_ + ch) * T_ + t) * D_;
    } else {
      dst = Kr + (size_t)((b * KV_ + (ch - 8)) * T_ + t) * D_;
    }
    dst[lane] = (bf16)o1;
    dst[lane + 64] = (bf16)o2;
  }
}

// ---------------------------------------------------------------------------
// Flash attention, sliding window + causal + softcap(50).
// grid (T/64, H, B); 4 waves/block, each wave owns 16 q-rows independently
// (no barriers -- waves have different KV ranges).  KV tiles of 32.
// kv head = hh % KV (reference reshapes q_kernel to (C,R,KV,D): hh = r*KV+h).
// Pl rows padded to 40 elements (80B = 5x16B, so b128 reads stay aligned):
// PV read lands 16 lanes on 8 bank-groups at 2-way (free) vs 8-way unpadded.
// Edge case (audited r3): for qb%32==16, qb>=544 the top rows of a band can
// have their entire first KV-tile below the window -> mnew==-inf no-op branch
// is REQUIRED (prevents exp(-inf-(-inf))=NaN poisoning l_r).
// ---------------------------------------------------------------------------
__global__ __launch_bounds__(256) void attn_kernel(const bf16* __restrict__ Qr,
                                                   const bf16* __restrict__ Kr,
                                                   const bf16* __restrict__ Vt,
                                                   bf16* __restrict__ attno) {
  __shared__ bf16 Pl[4][16][40];         // per-wave P tile (i x j'), padded
  const int qt = blockIdx.x, hh = blockIdx.y, b = blockIdx.z;
  const int h = hh & (KV_ - 1);
  const int w = threadIdx.x >> 6, lane = threadIdx.x & 63;
  const int lrow = lane & 15, lgrp = lane >> 4;
  const int qb = qt * 64 + w * 16;

  const bf16* Qb = Qr + ((size_t)(b * H_ + hh) * T_ + qb + lrow) * D_;
  const bf16* Kb = Kr + (size_t)(b * KV_ + h) * T_ * D_;
  const bf16* Vb = Vt + (size_t)(b * KV_ + h) * D_ * T_;

  bf16x8 aq[4];
#pragma unroll
  for (int dt = 0; dt < 4; ++dt)
    aq[dt] = *(const bf16x8*)(Qb + dt * 32 + lgrp * 8);

  const f32x4 fz = {0.f, 0.f, 0.f, 0.f};
  f32x4 o[8];
#pragma unroll
  for (int i = 0; i < 8; ++i) o[i] = fz;
  float m_r[4], l_r[4];
#pragma unroll
  for (int r = 0; r < 4; ++r) { m_r[r] = -__builtin_inff(); l_r[r] = 0.f; }

  int jlo = qb - (WIN_ - 1); if (jlo < 0) jlo = 0;
  for (int j0 = (jlo & ~31); j0 <= qb + 15; j0 += 32) {
    // S = Q K^T  (two 16x16 col-tiles)
    f32x4 sv0 = fz, sv1 = fz;
#pragma unroll
    for (int dt = 0; dt < 4; ++dt) {
      bf16x8 bk0 = *(const bf16x8*)(Kb + (size_t)(j0 + lrow) * D_ + dt * 32 + lgrp * 8);
      bf16x8 bk1 = *(const bf16x8*)(Kb + (size_t)(j0 + 16 + lrow) * D_ + dt * 32 + lgrp * 8);
      sv0 = __builtin_amdgcn_mfma_f32_16x16x32_bf16(aq[dt], bk0, sv0, 0, 0, 0);
      sv1 = __builtin_amdgcn_mfma_f32_16x16x32_bf16(aq[dt], bk1, sv1, 0, 0, 0);
    }
    // softcap + mask.  C/D layout: col = lane&15, row = (lane>>4)*4 + reg.
    float ca0[4], ca1[4];
    const int c0 = j0 + lrow, c1 = c0 + 16;
#pragma unroll
    for (int r = 0; r < 4; ++r) {
      const int i = qb + lgrp * 4 + r;
      float a0 = 50.f * tanhf(sv0[r] * 0.02f);
      float a1 = 50.f * tanhf(sv1[r] * 0.02f);
      ca0[r] = (c0 <= i && c0 >= i - (WIN_ - 1)) ? a0 : -__builtin_inff();
      ca1[r] = (c1 <= i && c1 >= i - (WIN_ - 1)) ? a1 : -__builtin_inff();
    }
    // online softmax (row-reduce across the 16 lanes of the lane-group)
    float alpha[4];
#pragma unroll
    for (int r = 0; r < 4; ++r) {
      float mx = fmaxf(ca0[r], ca1[r]);
#pragma unroll
      for (int d = 1; d < 16; d <<= 1) mx = fmaxf(mx, __shfl_xor(mx, d));
      const float mnew = fmaxf(m_r[r], mx);
      float p0, p1, al;
      if (mnew == -__builtin_inff()) {    // whole-row-invalid tile: no-op
        p0 = 0.f; p1 = 0.f; al = 1.f;
      } else {
        al = __expf(m_r[r] - mnew);       // exp(-inf)=0 on first valid tile
        p0 = __expf(ca0[r] - mnew);
        p1 = __expf(ca1[r] - mnew);
      }
      float rs = p0 + p1;
#pragma unroll
      for (int d = 1; d < 16; d <<= 1) rs += __shfl_xor(rs, d);
      m_r[r] = mnew;
      l_r[r] = l_r[r] * al + rs;
      alpha[r] = al;
      Pl[w][lgrp * 4 + r][lrow]      = (bf16)p0;
      Pl[w][lgrp * 4 + r][lrow + 16] = (bf16)p1;
    }
#pragma unroll
    for (int dt = 0; dt < 8; ++dt) {
      o[dt][0] *= alpha[0]; o[dt][1] *= alpha[1];
      o[dt][2] *= alpha[2]; o[dt][3] *= alpha[3];
    }
    // wave-local LDS fence (no __syncthreads: waves have divergent trip counts)
    asm volatile("s_waitcnt lgkmcnt(0)" ::: "memory");
    bf16x8 pa = *(const bf16x8*)(&Pl[w][lrow][lgrp * 8]);
#pragma unroll
    for (int dt = 0; dt < 8; ++dt) {
      bf16x8 bv = *(const bf16x8*)(Vb + (size_t)(dt * 16 + lrow) * T_ + j0 + lgrp * 8);
      o[dt] = __builtin_amdgcn_mfma_f32_16x16x32_bf16(pa, bv, o[dt], 0, 0, 0);
    }
  }
  // epilogue: concat layout [b*T + t][hh*D + d] -> GEMM-ready [4096][1024]
#pragma unroll
  for (int dt = 0; dt < 8; ++dt)
#pragma unroll
    for (int r = 0; r < 4; ++r) {
      const int i = qb + lgrp * 4 + r;
      attno[(size_t)(b * T_ + i) * (H_ * D_) + hh * D_ + dt * 16 + lrow] =
          (bf16)(o[dt][r] / l_r[r]);
    }
}

// ---------------------------------------------------------------------------
// bf16 GEMM, m97 structure: 128x128 tile, BK=64, 4 waves (2x2 of 64x64),
// global_load_lds width 16, single LDS buffer, 2 barriers/K-step.
// C[m][n] = sum_k A[m][k] * Bt[n][k]   (Bt = B^T, row-major [N][K])
// EPI: 0 = bf16 store; 1 = fp32 store + fp32 residual; 2 = bf16 store of
//      silu(gateb[idx]) * acc   (acc = up-projection)
// NOTE: known 16-way bank conflict on the sA/sB ds_read_b128 (stride 128B).
// T2 swizzle deliberately deferred: NULL on 2-phase structure (m228d/m252);
// pays only with the 8-phase schedule (next step once counters exist).
// T1 XCD swizzle considered & rejected (r3): all GEMM working sets are
// L3-resident; measured L3-fit case is -2% (m160), HBM-bound +10% N/A here.
// ---------------------------------------------------------------------------
template <int EPI>
__global__ __launch_bounds__(256) void gemm_bt_kernel(
    const bf16* __restrict__ A, const bf16* __restrict__ Bt,
    int N, int K,
    bf16* __restrict__ outb, float* __restrict__ outf,
    const float* __restrict__ residf, const bf16* __restrict__ gateb) {
  __shared__ bf16 sA[128][64];
  __shared__ bf16 sB[128][64];
  const int bm = blockIdx.y, bn = blockIdx.x;
  const int tid = threadIdx.x, w = tid >> 6, lane = tid & 63;
  const int wr = w >> 1, wc = w & 1;
  const int lrow = lane & 15, lgrp = lane >> 4;

  const bf16* Ab = A + (size_t)(bm * 128) * K;
  const bf16* Bb = Bt + (size_t)(bn * 128) * K;

  const f32x4 fz = {0.f, 0.f, 0.f, 0.f};
  f32x4 acc[4][4];
#pragma unroll
  for (int m = 0; m < 4; ++m)
#pragma unroll
    for (int n = 0; n < 4; ++n) acc[m][n] = fz;

  const int stg_row = w * 32 + (lane >> 3);        // +c*8 below
  const int stg_col = (lane & 7) * 8;              // elements (16B)

  for (int k0 = 0; k0 < K; k0 += 64) {
    __syncthreads();                               // readers of prev tile done
#pragma unroll
    for (int c = 0; c < 4; ++c) {
      const size_t ro = (size_t)(stg_row + c * 8) * K + k0 + stg_col;
      gload_lds16(Ab + ro, &sA[w * 32 + c * 8][0]);
      gload_lds16(Bb + ro, &sB[w * 32 + c * 8][0]);
    }
    __syncthreads();                               // drains vmcnt(0) first
#pragma unroll
    for (int kk = 0; kk < 2; ++kk) {
      bf16x8 af[4], bfr[4];
#pragma unroll
      for (int m = 0; m < 4; ++m)
        af[m] = *(const bf16x8*)(&sA[wr * 64 + m * 16 + lrow][kk * 32 + lgrp * 8]);
#pragma unroll
      for (int n = 0; n < 4; ++n)
        bfr[n] = *(const bf16x8*)(&sB[wc * 64 + n * 16 + lrow][kk * 32 + lgrp * 8]);
#pragma unroll
      for (int m = 0; m < 4; ++m)
#pragma unroll
        for (int n = 0; n < 4; ++n)
          acc[m][n] = __builtin_amdgcn_mfma_f32_16x16x32_bf16(af[m], bfr[n], acc[m][n], 0, 0, 0);
    }
  }

#pragma unroll
  for (int m = 0; m < 4; ++m) {
    const int row0 = bm * 128 + wr * 64 + m * 16 + lgrp * 4;
#pragma unroll
    for (int n = 0; n < 4; ++n) {
      const int col = bn * 128 + wc * 64 + n * 16 + lrow;
#pragma unroll
      for (int r = 0; r < 4; ++r) {
        const size_t idx = (size_t)(row0 + r) * N + col;
        const float v = acc[m][n][r];
        if (EPI == 0) {
          outb[idx] = (bf16)v;
        } else if (EPI == 1) {
          outf[idx] = v + residf[idx];
        } else {
          const float g = (float)gateb[idx];
          const float sg = g / (1.f + __expf(-g));
          outb[idx] = (bf16)(sg * v);
        }
      }
    }
  }
}

// ---------------------------------------------------------------------------
extern "C" void kernel_launch(void* const* d_in, const int* in_sizes, int n_in,
                              void* d_out, int out_size, void* d_ws, size_t ws_size,
                              hipStream_t stream) {
  const float* x      = (const float*)d_in[0];
  const float* qk_w   = (const float*)d_in[1];
  const float* kk_w   = (const float*)d_in[2];
  const float* vk_w   = (const float*)d_in[3];
  const float* ok_w   = (const float*)d_in[4];
  const float* ascale = (const float*)d_in[5];
  const float* mscale = (const float*)d_in[6];
  const float* gk_w   = (const float*)d_in[7];
  const float* uk_w   = (const float*)d_in[8];
  const float* dk_w   = (const float*)d_in[9];
  float* out = (float*)d_out;

  char* p = (char*)d_ws;
  auto alloc = [&](size_t bytes) {
    char* r = p;
    p += (bytes + 255) & ~(size_t)255;
    return r;
  };
  bf16*  Wqkv = (bf16*)alloc((size_t)2048 * 1024 * 2);   // [N=2048][K=1024] B^T
  bf16*  Wo   = (bf16*)alloc((size_t)1024 * 1024 * 2);   // [1024][1024]
  bf16*  Wgu  = (bf16*)alloc((size_t)8192 * 1024 * 2);   // gate rows 0..4095, up 4096..8191
  bf16*  Wdn  = (bf16*)alloc((size_t)1024 * 4096 * 2);   // [1024][4096]
  float* ct   = (float*)alloc((size_t)T_ * 64 * 4);
  float* st   = (float*)alloc((size_t)T_ * 64 * 4);
  bf16*  h1   = (bf16*)alloc((size_t)NTOK * C_ * 2);
  bf16*  qkv  = (bf16*)alloc((size_t)NTOK * 2048 * 2);
  bf16*  Qr   = (bf16*)alloc((size_t)B_ * H_ * T_ * D_ * 2);
  bf16*  Kr   = (bf16*)alloc((size_t)B_ * KV_ * T_ * D_ * 2);
  bf16*  Vt   = (bf16*)alloc((size_t)B_ * KV_ * T_ * D_ * 2);
  bf16*  attno= (bf16*)alloc((size_t)NTOK * 1024 * 2);
  float* x2   = (float*)alloc((size_t)NTOK * C_ * 4);
  bf16*  h2   = (bf16*)alloc((size_t)NTOK * C_ * 2);
  bf16*  gbuf = (bf16*)alloc((size_t)NTOK * HID_ * 2);
  bf16*  hmid = (bf16*)alloc((size_t)NTOK * HID_ * 2);
  (void)ws_size; (void)in_sizes; (void)n_in; (void)out_size;

  const dim3 tb(32, 8);

  // RoPE table + weight cast/transpose (independent of activations)
  rope_table_kernel<<<dim3((T_ * 64 + 255) / 256), dim3(256), 0, stream>>>(ct, st);
  transpose_cast_kernel<<<dim3(32, 32), tb, 0, stream>>>(qk_w, 1024, Wqkv, 1024, 1024, 1024);
  transpose_cast_kernel<<<dim3(16, 32), tb, 0, stream>>>(kk_w, 512, Wqkv + (size_t)1024 * 1024, 1024, 1024, 512);
  transpose_cast_kernel<<<dim3(16, 32), tb, 0, stream>>>(vk_w, 512, Wqkv + (size_t)1536 * 1024, 1024, 1024, 512);
  transpose_cast_kernel<<<dim3(32, 32), tb, 0, stream>>>(ok_w, 1024, Wo, 1024, 1024, 1024);
  transpose_cast_kernel<<<dim3(128, 32), tb, 0, stream>>>(gk_w, 4096, Wgu, 1024, 1024, 4096);
  transpose_cast_kernel<<<dim3(128, 32), tb, 0, stream>>>(uk_w, 4096, Wgu + (size_t)4096 * 1024, 1024, 1024, 4096);
  transpose_cast_kernel<<<dim3(32, 128), tb, 0, stream>>>(dk_w, 1024, Wdn, 4096, 4096, 1024);

  // Attention branch
  rmsnorm_kernel<<<dim3(NTOK), dim3(256), 0, stream>>>(x, ascale, h1);
  gemm_bt_kernel<0><<<dim3(16, 32), dim3(256), 0, stream>>>(h1, Wqkv, 2048, 1024, qkv, nullptr, nullptr, nullptr);
  rope_apply_kernel<<<dim3(NTOK), dim3(256), 0, stream>>>(qkv, ct, st, Qr, Kr);
  transpose_v_kernel<<<dim3(64, 4, 8), tb, 0, stream>>>(qkv, Vt);
  attn_kernel<<<dim3(32, 8, 2), dim3(256), 0, stream>>>(Qr, Kr, Vt, attno);
  gemm_bt_kernel<1><<<dim3(8, 32), dim3(256), 0, stream>>>(attno, Wo, 1024, 1024, nullptr, x2, x, nullptr);

  // MLP branch
  rmsnorm_kernel<<<dim3(NTOK), dim3(256), 0, stream>>>(x2, mscale, h2);
  gemm_bt_kernel<0><<<dim3(32, 32), dim3(256), 0, stream>>>(h2, Wgu, 4096, 1024, gbuf, nullptr, nullptr, nullptr);
  gemm_bt_kernel<2><<<dim3(32, 32), dim3(256), 0, stream>>>(h2, Wgu + (size_t)4096 * 1024, 4096, 1024, hmid, nullptr, nullptr, gbuf);
  gemm_bt_kernel<1><<<dim3(8, 32), dim3(256), 0, stream>>>(hmid, Wdn, 1024, 4096, nullptr, out, x2, nullptr);
}

// Round 7
// 458.206 us; speedup vs baseline: 1.0306x; 1.0306x over previous
//
#include <hip/hip_runtime.h>
#include <hip/hip_bf16.h>
#include <math.h>

// Problem constants (from reference)
#define B_   2
#define T_   2048
#define C_   1024
#define H_   8
#define KV_  4
#define D_   128
#define WIN_ 512
#define HID_ 4096
#define NTOK (B_*T_)          // 4096 tokens
#define QK_SCALE 0.08838834764831845f   // rsqrt(128)

typedef __bf16 bf16;
typedef __attribute__((ext_vector_type(8))) __bf16 bf16x8;   // MFMA A/B frag (4 VGPR)
typedef __attribute__((ext_vector_type(4))) __bf16 bf16x4;
typedef __attribute__((ext_vector_type(4))) float  f32x4;    // MFMA C/D frag

#define AS1 __attribute__((address_space(1)))
#define AS3 __attribute__((address_space(3)))

// async global->LDS, 16B/lane. LDS dest is wave-uniform base + lane*16 (m97 pattern).
__device__ __forceinline__ void gload_lds16(const bf16* g, bf16* l) {
  __builtin_amdgcn_global_load_lds((const AS1 void*)g, (AS3 void*)l, 16, 0, 0);
}

// ---------------------------------------------------------------------------
// Weight cast+transpose: dst[n][k] = (bf16)src[k][n].  B^T layout so GEMM
// B-fragments are 8-contiguous-k b128 reads (layout proven by m92/m97).
// grid: (N/32, K/32), block (32,8)
// ---------------------------------------------------------------------------
__global__ void transpose_cast_kernel(const float* __restrict__ src, int ldsrc,
                                      bf16* __restrict__ dst, int lddst,
                                      int K, int N) {
  __shared__ float tile[32][33];
  const int n0 = blockIdx.x * 32, k0 = blockIdx.y * 32;
  const int tx = threadIdx.x, ty = threadIdx.y;
#pragma unroll
  for (int i = 0; i < 32; i += 8)
    tile[ty + i][tx] = src[(size_t)(k0 + ty + i) * ldsrc + n0 + tx];
  __syncthreads();
#pragma unroll
  for (int i = 0; i < 32; i += 8)
    dst[(size_t)(n0 + ty + i) * lddst + k0 + tx] = (bf16)tile[tx][ty + i];
}

// V transpose: vt[(b*KV+h)*D + d][t] = qkv[b*T+t][1536 + h*128 + d]
// grid: (T/32, D/32, B*KV), block (32,8)
__global__ void transpose_v_kernel(const bf16* __restrict__ qkv, bf16* __restrict__ vt) {
  __shared__ bf16 tile[32][33];
  const int bh = blockIdx.z, b = bh >> 2, h = bh & 3;
  const int t0 = blockIdx.x * 32, d0 = blockIdx.y * 32;
  const int tx = threadIdx.x, ty = threadIdx.y;
#pragma unroll
  for (int i = 0; i < 32; i += 8)
    tile[ty + i][tx] = qkv[(size_t)(b * T_ + t0 + ty + i) * 2048 + 1536 + h * 128 + d0 + tx];
  __syncthreads();
#pragma unroll
  for (int i = 0; i < 32; i += 8)
    vt[(size_t)((b * KV_ + h) * D_ + d0 + ty + i) * T_ + t0 + tx] = tile[tx][ty + i];
}

// ---------------------------------------------------------------------------
// RoPE sin/cos table: [T][64] each (the two D/2 halves share angles)
// ---------------------------------------------------------------------------
__global__ void rope_table_kernel(float* __restrict__ ct, float* __restrict__ st) {
  const int idx = blockIdx.x * 256 + threadIdx.x;
  if (idx >= T_ * 64) return;
  const int t = idx >> 6, i = idx & 63;
  const float inv = __expf(-(float)i * (1.0f / 64.0f) * logf(10000.0f));
  const float a = (float)t * inv;
  ct[idx] = cosf(a);
  st[idx] = sinf(a);
}

// ---------------------------------------------------------------------------
// RMSNorm (fp32 in) -> bf16 out.  One block per row, 256 threads * float4.
// ---------------------------------------------------------------------------
__global__ __launch_bounds__(256) void rmsnorm_kernel(const float* __restrict__ x,
                                                      const float* __restrict__ scale,
                                                      bf16* __restrict__ out) {
  const int row = blockIdx.x;
  const float* xr = x + (size_t)row * C_;
  const int tid = threadIdx.x;
  float4 v = ((const float4*)xr)[tid];
  float ss = v.x * v.x + v.y * v.y + v.z * v.z + v.w * v.w;
#pragma unroll
  for (int o = 32; o > 0; o >>= 1) ss += __shfl_down(ss, o);
  __shared__ float part[4];
  __shared__ float total;
  if ((tid & 63) == 0) part[tid >> 6] = ss;
  __syncthreads();
  if (tid == 0) total = part[0] + part[1] + part[2] + part[3];
  __syncthreads();
  const float r = rsqrtf(total * (1.0f / C_) + 1e-6f);
  float4 sc = ((const float4*)scale)[tid];
  bf16x4 o4;
  o4[0] = (bf16)(v.x * r * (1.f + sc.x));
  o4[1] = (bf16)(v.y * r * (1.f + sc.y));
  o4[2] = (bf16)(v.z * r * (1.f + sc.z));
  o4[3] = (bf16)(v.w * r * (1.f + sc.w));
  *(bf16x4*)(out + (size_t)row * C_ + tid * 4) = o4;
}

// ---------------------------------------------------------------------------
// RoPE apply + scatter into attention layouts.
// qkv row layout: cols [0,1024) q heads (hh = r*KV+h), [1024,1536) k, rest v.
// Qr[b][hh][t][d] (scaled by rsqrt(D)), Kr[b][h][t][d].  V handled separately.
// grid: NTOK blocks, 256 threads (4 waves x 3 head-chunks, lane = rope pair idx)
// ---------------------------------------------------------------------------
__global__ __launch_bounds__(256) void rope_apply_kernel(const bf16* __restrict__ qkv,
                                                         const float* __restrict__ ct,
                                                         const float* __restrict__ st,
                                                         bf16* __restrict__ Qr,
                                                         bf16* __restrict__ Kr) {
  const int row = blockIdx.x;            // b*T + t
  const int b = row >> 11, t = row & (T_ - 1);
  const int w = threadIdx.x >> 6, lane = threadIdx.x & 63;
  const float c = ct[t * 64 + lane], s = st[t * 64 + lane];
#pragma unroll
  for (int q = 0; q < 3; ++q) {
    const int ch = w * 3 + q;            // 0..11  (8 q-heads, 4 k-heads)
    const bf16* src = qkv + (size_t)row * 2048 + ch * 128;
    float x1 = (float)src[lane], x2 = (float)src[lane + 64];
    float o1 = x1 * c - x2 * s;
    float o2 = x2 * c + x1 * s;
    bf16* dst;
    if (ch < 8) {
      o1 *= QK_SCALE; o2 *= QK_SCALE;
      dst = Qr + (size_t)((b * H_ + ch) * T_ + t) * D_;
    } else {
      dst = Kr + (size_t)((b * KV_ + (ch - 8)) * T_ + t) * D_;
    }
    dst[lane] = (bf16)o1;
    dst[lane + 64] = (bf16)o2;
  }
}

// ---------------------------------------------------------------------------
// Flash attention, sliding window + causal + softcap(50).
// grid (T/64, H, B); 4 waves/block, each wave owns 16 q-rows independently
// (no barriers -- waves have different KV ranges).  KV tiles of 32.
// kv head = hh % KV (reference reshapes q_kernel to (C,R,KV,D): hh = r*KV+h).
// Pl rows padded to 40 elements (80B = 5x16B, so b128 reads stay aligned):
// PV read lands 16 lanes on 8 bank-groups at 2-way (free) vs 8-way unpadded.
// Edge case (audited r3): for qb%32==16, qb>=544 the top rows of a band can
// have their entire first KV-tile below the window -> mnew==-inf no-op branch
// is REQUIRED (prevents exp(-inf-(-inf))=NaN poisoning l_r).
// ---------------------------------------------------------------------------
__global__ __launch_bounds__(256) void attn_kernel(const bf16* __restrict__ Qr,
                                                   const bf16* __restrict__ Kr,
                                                   const bf16* __restrict__ Vt,
                                                   bf16* __restrict__ attno) {
  __shared__ bf16 Pl[4][16][40];         // per-wave P tile (i x j'), padded
  const int qt = blockIdx.x, hh = blockIdx.y, b = blockIdx.z;
  const int h = hh & (KV_ - 1);
  const int w = threadIdx.x >> 6, lane = threadIdx.x & 63;
  const int lrow = lane & 15, lgrp = lane >> 4;
  const int qb = qt * 64 + w * 16;

  const bf16* Qb = Qr + ((size_t)(b * H_ + hh) * T_ + qb + lrow) * D_;
  const bf16* Kb = Kr + (size_t)(b * KV_ + h) * T_ * D_;
  const bf16* Vb = Vt + (size_t)(b * KV_ + h) * D_ * T_;

  bf16x8 aq[4];
#pragma unroll
  for (int dt = 0; dt < 4; ++dt)
    aq[dt] = *(const bf16x8*)(Qb + dt * 32 + lgrp * 8);

  const f32x4 fz = {0.f, 0.f, 0.f, 0.f};
  f32x4 o[8];
#pragma unroll
  for (int i = 0; i < 8; ++i) o[i] = fz;
  float m_r[4], l_r[4];
#pragma unroll
  for (int r = 0; r < 4; ++r) { m_r[r] = -__builtin_inff(); l_r[r] = 0.f; }

  int jlo = qb - (WIN_ - 1); if (jlo < 0) jlo = 0;
  for (int j0 = (jlo & ~31); j0 <= qb + 15; j0 += 32) {
    // S = Q K^T  (two 16x16 col-tiles)
    f32x4 sv0 = fz, sv1 = fz;
#pragma unroll
    for (int dt = 0; dt < 4; ++dt) {
      bf16x8 bk0 = *(const bf16x8*)(Kb + (size_t)(j0 + lrow) * D_ + dt * 32 + lgrp * 8);
      bf16x8 bk1 = *(const bf16x8*)(Kb + (size_t)(j0 + 16 + lrow) * D_ + dt * 32 + lgrp * 8);
      sv0 = __builtin_amdgcn_mfma_f32_16x16x32_bf16(aq[dt], bk0, sv0, 0, 0, 0);
      sv1 = __builtin_amdgcn_mfma_f32_16x16x32_bf16(aq[dt], bk1, sv1, 0, 0, 0);
    }
    // softcap + mask.  C/D layout: col = lane&15, row = (lane>>4)*4 + reg.
    float ca0[4], ca1[4];
    const int c0 = j0 + lrow, c1 = c0 + 16;
#pragma unroll
    for (int r = 0; r < 4; ++r) {
      const int i = qb + lgrp * 4 + r;
      float a0 = 50.f * tanhf(sv0[r] * 0.02f);
      float a1 = 50.f * tanhf(sv1[r] * 0.02f);
      ca0[r] = (c0 <= i && c0 >= i - (WIN_ - 1)) ? a0 : -__builtin_inff();
      ca1[r] = (c1 <= i && c1 >= i - (WIN_ - 1)) ? a1 : -__builtin_inff();
    }
    // online softmax (row-reduce across the 16 lanes of the lane-group)
    float alpha[4];
#pragma unroll
    for (int r = 0; r < 4; ++r) {
      float mx = fmaxf(ca0[r], ca1[r]);
#pragma unroll
      for (int d = 1; d < 16; d <<= 1) mx = fmaxf(mx, __shfl_xor(mx, d));
      const float mnew = fmaxf(m_r[r], mx);
      float p0, p1, al;
      if (mnew == -__builtin_inff()) {    // whole-row-invalid tile: no-op
        p0 = 0.f; p1 = 0.f; al = 1.f;
      } else {
        al = __expf(m_r[r] - mnew);       // exp(-inf)=0 on first valid tile
        p0 = __expf(ca0[r] - mnew);
        p1 = __expf(ca1[r] - mnew);
      }
      float rs = p0 + p1;
#pragma unroll
      for (int d = 1; d < 16; d <<= 1) rs += __shfl_xor(rs, d);
      m_r[r] = mnew;
      l_r[r] = l_r[r] * al + rs;
      alpha[r] = al;
      Pl[w][lgrp * 4 + r][lrow]      = (bf16)p0;
      Pl[w][lgrp * 4 + r][lrow + 16] = (bf16)p1;
    }
#pragma unroll
    for (int dt = 0; dt < 8; ++dt) {
      o[dt][0] *= alpha[0]; o[dt][1] *= alpha[1];
      o[dt][2] *= alpha[2]; o[dt][3] *= alpha[3];
    }
    // wave-local LDS fence (no __syncthreads: waves have divergent trip counts)
    asm volatile("s_waitcnt lgkmcnt(0)" ::: "memory");
    bf16x8 pa = *(const bf16x8*)(&Pl[w][lrow][lgrp * 8]);
#pragma unroll
    for (int dt = 0; dt < 8; ++dt) {
      bf16x8 bv = *(const bf16x8*)(Vb + (size_t)(dt * 16 + lrow) * T_ + j0 + lgrp * 8);
      o[dt] = __builtin_amdgcn_mfma_f32_16x16x32_bf16(pa, bv, o[dt], 0, 0, 0);
    }
  }
  // epilogue: concat layout [b*T + t][hh*D + d] -> GEMM-ready [4096][1024]
#pragma unroll
  for (int dt = 0; dt < 8; ++dt)
#pragma unroll
    for (int r = 0; r < 4; ++r) {
      const int i = qb + lgrp * 4 + r;
      attno[(size_t)(b * T_ + i) * (H_ * D_) + hh * D_ + dt * 16 + lrow] =
          (bf16)(o[dt][r] / l_r[r]);
    }
}

// ---------------------------------------------------------------------------
// bf16 GEMM, m97 structure: BM x 128 tile, BK=64, 4 waves (2x2), each wave
// (BM/2) x 64, MF = BM/32 m-frags.  global_load_lds width 16, single LDS
// buffer, 2 barriers/K-step.  C[m][n] = sum_k A[m][k] * Bt[n][k].
// EPI: 0 = bf16 store; 1 = fp32 store + fp32 residual; 2 = bf16 store of
//      silu(gateb[idx]) * acc   (acc = up-projection)
// R4 evidence: down GEMM (grid 256 = 1 block/CU) ran 90us, Occupancy 10.5%,
// MfmaUtil 14.6% -- latency-bound on the vmcnt(0)+barrier drain with no
// co-resident block to overlap (m114 mechanism absent).  M*N/128^2 = 256
// tiles exactly for N=1024, so BM=64 (grid 512 = 2 blocks/CU) is the
// smallest-diff occupancy fix for out-proj + down.  [UNBENCHED r5/r6: infra
// failures -- prediction: down 90->~55us, Occupancy 10.5->21%, total ~400us]
// T2 swizzle still deferred: NULL on 2-phase structure (m228d/m252).
// ---------------------------------------------------------------------------
template <int EPI, int BM>
__global__ __launch_bounds__(256) void gemm_bt_kernel(
    const bf16* __restrict__ A, const bf16* __restrict__ Bt,
    int N, int K,
    bf16* __restrict__ outb, float* __restrict__ outf,
    const float* __restrict__ residf, const bf16* __restrict__ gateb) {
  constexpr int MF = BM / 32;                    // m-frags per wave
  __shared__ bf16 sA[BM][64];
  __shared__ bf16 sB[128][64];
  const int bm = blockIdx.y, bn = blockIdx.x;
  const int tid = threadIdx.x, w = tid >> 6, lane = tid & 63;
  const int wr = w >> 1, wc = w & 1;
  const int lrow = lane & 15, lgrp = lane >> 4;

  const bf16* Ab = A + (size_t)(bm * BM) * K;
  const bf16* Bb = Bt + (size_t)(bn * 128) * K;

  const f32x4 fz = {0.f, 0.f, 0.f, 0.f};
  f32x4 acc[MF][4];
#pragma unroll
  for (int m = 0; m < MF; ++m)
#pragma unroll
    for (int n = 0; n < 4; ++n) acc[m][n] = fz;

  const int stg_row = lane >> 3;                 // 0..7 within a wave's 8 rows
  const int stg_col = (lane & 7) * 8;            // elements (16B)

  for (int k0 = 0; k0 < K; k0 += 64) {
    __syncthreads();                             // readers of prev tile done
#pragma unroll
    for (int c = 0; c < MF; ++c) {               // A: BM rows, 32 rows/pass
      const int r = c * 32 + w * 8;
      gload_lds16(Ab + (size_t)(r + stg_row) * K + k0 + stg_col, &sA[r][0]);
    }
#pragma unroll
    for (int c = 0; c < 4; ++c) {                // B: 128 rows
      const int r = c * 32 + w * 8;
      gload_lds16(Bb + (size_t)(r + stg_row) * K + k0 + stg_col, &sB[r][0]);
    }
    __syncthreads();                             // drains vmcnt(0) first
#pragma unroll
    for (int kk = 0; kk < 2; ++kk) {
      bf16x8 af[MF], bfr[4];
#pragma unroll
      for (int m = 0; m < MF; ++m)
        af[m] = *(const bf16x8*)(&sA[wr * (BM / 2) + m * 16 + lrow][kk * 32 + lgrp * 8]);
#pragma unroll
      for (int n = 0; n < 4; ++n)
        bfr[n] = *(const bf16x8*)(&sB[wc * 64 + n * 16 + lrow][kk * 32 + lgrp * 8]);
#pragma unroll
      for (int m = 0; m < MF; ++m)
#pragma unroll
        for (int n = 0; n < 4; ++n)
          acc[m][n] = __builtin_amdgcn_mfma_f32_16x16x32_bf16(af[m], bfr[n], acc[m][n], 0, 0, 0);
    }
  }

#pragma unroll
  for (int m = 0; m < MF; ++m) {
    const int row0 = bm * BM + wr * (BM / 2) + m * 16 + lgrp * 4;
#pragma unroll
    for (int n = 0; n < 4; ++n) {
      const int col = bn * 128 + wc * 64 + n * 16 + lrow;
#pragma unroll
      for (int r = 0; r < 4; ++r) {
        const size_t idx = (size_t)(row0 + r) * N + col;
        const float v = acc[m][n][r];
        if (EPI == 0) {
          outb[idx] = (bf16)v;
        } else if (EPI == 1) {
          outf[idx] = v + residf[idx];
        } else {
          const float g = (float)gateb[idx];
          const float sg = g / (1.f + __expf(-g));
          outb[idx] = (bf16)(sg * v);
        }
      }
    }
  }
}

// ---------------------------------------------------------------------------
extern "C" void kernel_launch(void* const* d_in, const int* in_sizes, int n_in,
                              void* d_out, int out_size, void* d_ws, size_t ws_size,
                              hipStream_t stream) {
  const float* x      = (const float*)d_in[0];
  const float* qk_w   = (const float*)d_in[1];
  const float* kk_w   = (const float*)d_in[2];
  const float* vk_w   = (const float*)d_in[3];
  const float* ok_w   = (const float*)d_in[4];
  const float* ascale = (const float*)d_in[5];
  const float* mscale = (const float*)d_in[6];
  const float* gk_w   = (const float*)d_in[7];
  const float* uk_w   = (const float*)d_in[8];
  const float* dk_w   = (const float*)d_in[9];
  float* out = (float*)d_out;

  char* p = (char*)d_ws;
  auto alloc = [&](size_t bytes) {
    char* r = p;
    p += (bytes + 255) & ~(size_t)255;
    return r;
  };
  bf16*  Wqkv = (bf16*)alloc((size_t)2048 * 1024 * 2);   // [N=2048][K=1024] B^T
  bf16*  Wo   = (bf16*)alloc((size_t)1024 * 1024 * 2);   // [1024][1024]
  bf16*  Wgu  = (bf16*)alloc((size_t)8192 * 1024 * 2);   // gate rows 0..4095, up 4096..8191
  bf16*  Wdn  = (bf16*)alloc((size_t)1024 * 4096 * 2);   // [1024][4096]
  float* ct   = (float*)alloc((size_t)T_ * 64 * 4);
  float* st   = (float*)alloc((size_t)T_ * 64 * 4);
  bf16*  h1   = (bf16*)alloc((size_t)NTOK * C_ * 2);
  bf16*  qkv  = (bf16*)alloc((size_t)NTOK * 2048 * 2);
  bf16*  Qr   = (bf16*)alloc((size_t)B_ * H_ * T_ * D_ * 2);
  bf16*  Kr   = (bf16*)alloc((size_t)B_ * KV_ * T_ * D_ * 2);
  bf16*  Vt   = (bf16*)alloc((size_t)B_ * KV_ * T_ * D_ * 2);
  bf16*  attno= (bf16*)alloc((size_t)NTOK * 1024 * 2);
  float* x2   = (float*)alloc((size_t)NTOK * C_ * 4);
  bf16*  h2   = (bf16*)alloc((size_t)NTOK * C_ * 2);
  bf16*  gbuf = (bf16*)alloc((size_t)NTOK * HID_ * 2);
  bf16*  hmid = (bf16*)alloc((size_t)NTOK * HID_ * 2);
  (void)ws_size; (void)in_sizes; (void)n_in; (void)out_size;

  const dim3 tb(32, 8);

  // RoPE table + weight cast/transpose (independent of activations)
  rope_table_kernel<<<dim3((T_ * 64 + 255) / 256), dim3(256), 0, stream>>>(ct, st);
  transpose_cast_kernel<<<dim3(32, 32), tb, 0, stream>>>(qk_w, 1024, Wqkv, 1024, 1024, 1024);
  transpose_cast_kernel<<<dim3(16, 32), tb, 0, stream>>>(kk_w, 512, Wqkv + (size_t)1024 * 1024, 1024, 1024, 512);
  transpose_cast_kernel<<<dim3(16, 32), tb, 0, stream>>>(vk_w, 512, Wqkv + (size_t)1536 * 1024, 1024, 1024, 512);
  transpose_cast_kernel<<<dim3(32, 32), tb, 0, stream>>>(ok_w, 1024, Wo, 1024, 1024, 1024);
  transpose_cast_kernel<<<dim3(128, 32), tb, 0, stream>>>(gk_w, 4096, Wgu, 1024, 1024, 4096);
  transpose_cast_kernel<<<dim3(128, 32), tb, 0, stream>>>(uk_w, 4096, Wgu + (size_t)4096 * 1024, 1024, 1024, 4096);
  transpose_cast_kernel<<<dim3(32, 128), tb, 0, stream>>>(dk_w, 1024, Wdn, 4096, 4096, 1024);

  // Attention branch
  rmsnorm_kernel<<<dim3(NTOK), dim3(256), 0, stream>>>(x, ascale, h1);
  gemm_bt_kernel<0, 128><<<dim3(16, 32), dim3(256), 0, stream>>>(h1, Wqkv, 2048, 1024, qkv, nullptr, nullptr, nullptr);
  rope_apply_kernel<<<dim3(NTOK), dim3(256), 0, stream>>>(qkv, ct, st, Qr, Kr);
  transpose_v_kernel<<<dim3(64, 4, 8), tb, 0, stream>>>(qkv, Vt);
  attn_kernel<<<dim3(32, 8, 2), dim3(256), 0, stream>>>(Qr, Kr, Vt, attno);
  // out-proj: BM=64 -> grid (8,64)=512 blocks = 2 blocks/CU (was 256 = 1/CU)
  gemm_bt_kernel<1, 64><<<dim3(8, 64), dim3(256), 0, stream>>>(attno, Wo, 1024, 1024, nullptr, x2, x, nullptr);

  // MLP branch
  rmsnorm_kernel<<<dim3(NTOK), dim3(256), 0, stream>>>(x2, mscale, h2);
  gemm_bt_kernel<0, 128><<<dim3(32, 32), dim3(256), 0, stream>>>(h2, Wgu, 4096, 1024, gbuf, nullptr, nullptr, nullptr);
  gemm_bt_kernel<2, 128><<<dim3(32, 32), dim3(256), 0, stream>>>(h2, Wgu + (size_t)4096 * 1024, 4096, 1024, hmid, nullptr, nullptr, gbuf);
  // down: BM=64 -> grid (8,64)=512 blocks = 2 blocks/CU (was 256 = 1/CU, 90us hot spot)
  gemm_bt_kernel<1, 64><<<dim3(8, 64), dim3(256), 0, stream>>>(hmid, Wdn, 1024, 4096, nullptr, out, x2, nullptr);
}

// Round 8
// 450.444 us; speedup vs baseline: 1.0484x; 1.0172x over previous
//
#include <hip/hip_runtime.h>
#include <hip/hip_bf16.h>
#include <math.h>

// Problem constants (from reference)
#define B_   2
#define T_   2048
#define C_   1024
#define H_   8
#define KV_  4
#define D_   128
#define WIN_ 512
#define HID_ 4096
#define NTOK (B_*T_)          // 4096 tokens
#define QK_SCALE 0.08838834764831845f   // rsqrt(128)

typedef __bf16 bf16;
typedef __attribute__((ext_vector_type(8))) __bf16 bf16x8;   // MFMA A/B frag (4 VGPR)
typedef __attribute__((ext_vector_type(4))) __bf16 bf16x4;
typedef __attribute__((ext_vector_type(4))) float  f32x4;    // MFMA C/D frag

#define AS1 __attribute__((address_space(1)))
#define AS3 __attribute__((address_space(3)))

// async global->LDS, 16B/lane. LDS dest is wave-uniform base + lane*16 (m97 pattern).
__device__ __forceinline__ void gload_lds16(const bf16* g, bf16* l) {
  __builtin_amdgcn_global_load_lds((const AS1 void*)g, (AS3 void*)l, 16, 0, 0);
}

// ---------------------------------------------------------------------------
// Weight cast+transpose: dst[n][k] = (bf16)src[k][n].  B^T layout so GEMM
// B-fragments are 8-contiguous-k b128 reads (layout proven by m92/m97).
// grid: (N/32, K/32), block (32,8)
// ---------------------------------------------------------------------------
__global__ void transpose_cast_kernel(const float* __restrict__ src, int ldsrc,
                                      bf16* __restrict__ dst, int lddst,
                                      int K, int N) {
  __shared__ float tile[32][33];
  const int n0 = blockIdx.x * 32, k0 = blockIdx.y * 32;
  const int tx = threadIdx.x, ty = threadIdx.y;
#pragma unroll
  for (int i = 0; i < 32; i += 8)
    tile[ty + i][tx] = src[(size_t)(k0 + ty + i) * ldsrc + n0 + tx];
  __syncthreads();
#pragma unroll
  for (int i = 0; i < 32; i += 8)
    dst[(size_t)(n0 + ty + i) * lddst + k0 + tx] = (bf16)tile[tx][ty + i];
}

// V transpose: vt[(b*KV+h)*D + d][t] = qkv[b*T+t][1536 + h*128 + d]
// grid: (T/32, D/32, B*KV), block (32,8)
__global__ void transpose_v_kernel(const bf16* __restrict__ qkv, bf16* __restrict__ vt) {
  __shared__ bf16 tile[32][33];
  const int bh = blockIdx.z, b = bh >> 2, h = bh & 3;
  const int t0 = blockIdx.x * 32, d0 = blockIdx.y * 32;
  const int tx = threadIdx.x, ty = threadIdx.y;
#pragma unroll
  for (int i = 0; i < 32; i += 8)
    tile[ty + i][tx] = qkv[(size_t)(b * T_ + t0 + ty + i) * 2048 + 1536 + h * 128 + d0 + tx];
  __syncthreads();
#pragma unroll
  for (int i = 0; i < 32; i += 8)
    vt[(size_t)((b * KV_ + h) * D_ + d0 + ty + i) * T_ + t0 + tx] = tile[tx][ty + i];
}

// ---------------------------------------------------------------------------
// RoPE sin/cos table: [T][64] each (the two D/2 halves share angles)
// ---------------------------------------------------------------------------
__global__ void rope_table_kernel(float* __restrict__ ct, float* __restrict__ st) {
  const int idx = blockIdx.x * 256 + threadIdx.x;
  if (idx >= T_ * 64) return;
  const int t = idx >> 6, i = idx & 63;
  const float inv = __expf(-(float)i * (1.0f / 64.0f) * logf(10000.0f));
  const float a = (float)t * inv;
  ct[idx] = cosf(a);
  st[idx] = sinf(a);
}

// ---------------------------------------------------------------------------
// RMSNorm (fp32 in) -> bf16 out.  One block per row, 256 threads * float4.
// ---------------------------------------------------------------------------
__global__ __launch_bounds__(256) void rmsnorm_kernel(const float* __restrict__ x,
                                                      const float* __restrict__ scale,
                                                      bf16* __restrict__ out) {
  const int row = blockIdx.x;
  const float* xr = x + (size_t)row * C_;
  const int tid = threadIdx.x;
  float4 v = ((const float4*)xr)[tid];
  float ss = v.x * v.x + v.y * v.y + v.z * v.z + v.w * v.w;
#pragma unroll
  for (int o = 32; o > 0; o >>= 1) ss += __shfl_down(ss, o);
  __shared__ float part[4];
  __shared__ float total;
  if ((tid & 63) == 0) part[tid >> 6] = ss;
  __syncthreads();
  if (tid == 0) total = part[0] + part[1] + part[2] + part[3];
  __syncthreads();
  const float r = rsqrtf(total * (1.0f / C_) + 1e-6f);
  float4 sc = ((const float4*)scale)[tid];
  bf16x4 o4;
  o4[0] = (bf16)(v.x * r * (1.f + sc.x));
  o4[1] = (bf16)(v.y * r * (1.f + sc.y));
  o4[2] = (bf16)(v.z * r * (1.f + sc.z));
  o4[3] = (bf16)(v.w * r * (1.f + sc.w));
  *(bf16x4*)(out + (size_t)row * C_ + tid * 4) = o4;
}

// ---------------------------------------------------------------------------
// RoPE apply + scatter into attention layouts.
// qkv row layout: cols [0,1024) q heads (hh = r*KV+h), [1024,1536) k, rest v.
// Qr[b][hh][t][d] (scaled by rsqrt(D)), Kr[b][h][t][d].  V handled separately.
// grid: NTOK blocks, 256 threads (4 waves x 3 head-chunks, lane = rope pair idx)
// ---------------------------------------------------------------------------
__global__ __launch_bounds__(256) void rope_apply_kernel(const bf16* __restrict__ qkv,
                                                         const float* __restrict__ ct,
                                                         const float* __restrict__ st,
                                                         bf16* __restrict__ Qr,
                                                         bf16* __restrict__ Kr) {
  const int row = blockIdx.x;            // b*T + t
  const int b = row >> 11, t = row & (T_ - 1);
  const int w = threadIdx.x >> 6, lane = threadIdx.x & 63;
  const float c = ct[t * 64 + lane], s = st[t * 64 + lane];
#pragma unroll
  for (int q = 0; q < 3; ++q) {
    const int ch = w * 3 + q;            // 0..11  (8 q-heads, 4 k-heads)
    const bf16* src = qkv + (size_t)row * 2048 + ch * 128;
    float x1 = (float)src[lane], x2 = (float)src[lane + 64];
    float o1 = x1 * c - x2 * s;
    float o2 = x2 * c + x1 * s;
    bf16* dst;
    if (ch < 8) {
      o1 *= QK_SCALE; o2 *= QK_SCALE;
      dst = Qr + (size_t)((b * H_ + ch) * T_ + t) * D_;
    } else {
      dst = Kr + (size_t)((b * KV_ + (ch - 8)) * T_ + t) * D_;
    }
    dst[lane] = (bf16)o1;
    dst[lane + 64] = (bf16)o2;
  }
}

// ---------------------------------------------------------------------------
// Flash attention, sliding window + causal + softcap(50).
// grid (T/64, H, B); 4 waves/block, each wave owns 16 q-rows independently
// (no barriers -- waves have different KV ranges).  KV tiles of 32.
// kv head = hh % KV (reference reshapes q_kernel to (C,R,KV,D): hh = r*KV+h).
// Pl rows padded to 40 elements (80B = 5x16B, so b128 reads stay aligned):
// PV read lands 16 lanes on 8 bank-groups at 2-way (free) vs 8-way unpadded.
// Edge case (audited r3): for qb%32==16, qb>=544 the top rows of a band can
// have their entire first KV-tile below the window -> mnew==-inf no-op branch
// is REQUIRED (prevents exp(-inf-(-inf))=NaN poisoning l_r).
// ---------------------------------------------------------------------------
__global__ __launch_bounds__(256) void attn_kernel(const bf16* __restrict__ Qr,
                                                   const bf16* __restrict__ Kr,
                                                   const bf16* __restrict__ Vt,
                                                   bf16* __restrict__ attno) {
  __shared__ bf16 Pl[4][16][40];         // per-wave P tile (i x j'), padded
  const int qt = blockIdx.x, hh = blockIdx.y, b = blockIdx.z;
  const int h = hh & (KV_ - 1);
  const int w = threadIdx.x >> 6, lane = threadIdx.x & 63;
  const int lrow = lane & 15, lgrp = lane >> 4;
  const int qb = qt * 64 + w * 16;

  const bf16* Qb = Qr + ((size_t)(b * H_ + hh) * T_ + qb + lrow) * D_;
  const bf16* Kb = Kr + (size_t)(b * KV_ + h) * T_ * D_;
  const bf16* Vb = Vt + (size_t)(b * KV_ + h) * D_ * T_;

  bf16x8 aq[4];
#pragma unroll
  for (int dt = 0; dt < 4; ++dt)
    aq[dt] = *(const bf16x8*)(Qb + dt * 32 + lgrp * 8);

  const f32x4 fz = {0.f, 0.f, 0.f, 0.f};
  f32x4 o[8];
#pragma unroll
  for (int i = 0; i < 8; ++i) o[i] = fz;
  float m_r[4], l_r[4];
#pragma unroll
  for (int r = 0; r < 4; ++r) { m_r[r] = -__builtin_inff(); l_r[r] = 0.f; }

  int jlo = qb - (WIN_ - 1); if (jlo < 0) jlo = 0;
  for (int j0 = (jlo & ~31); j0 <= qb + 15; j0 += 32) {
    // S = Q K^T  (two 16x16 col-tiles)
    f32x4 sv0 = fz, sv1 = fz;
#pragma unroll
    for (int dt = 0; dt < 4; ++dt) {
      bf16x8 bk0 = *(const bf16x8*)(Kb + (size_t)(j0 + lrow) * D_ + dt * 32 + lgrp * 8);
      bf16x8 bk1 = *(const bf16x8*)(Kb + (size_t)(j0 + 16 + lrow) * D_ + dt * 32 + lgrp * 8);
      sv0 = __builtin_amdgcn_mfma_f32_16x16x32_bf16(aq[dt], bk0, sv0, 0, 0, 0);
      sv1 = __builtin_amdgcn_mfma_f32_16x16x32_bf16(aq[dt], bk1, sv1, 0, 0, 0);
    }
    // softcap + mask.  C/D layout: col = lane&15, row = (lane>>4)*4 + reg.
    float ca0[4], ca1[4];
    const int c0 = j0 + lrow, c1 = c0 + 16;
#pragma unroll
    for (int r = 0; r < 4; ++r) {
      const int i = qb + lgrp * 4 + r;
      float a0 = 50.f * tanhf(sv0[r] * 0.02f);
      float a1 = 50.f * tanhf(sv1[r] * 0.02f);
      ca0[r] = (c0 <= i && c0 >= i - (WIN_ - 1)) ? a0 : -__builtin_inff();
      ca1[r] = (c1 <= i && c1 >= i - (WIN_ - 1)) ? a1 : -__builtin_inff();
    }
    // online softmax (row-reduce across the 16 lanes of the lane-group)
    float alpha[4];
#pragma unroll
    for (int r = 0; r < 4; ++r) {
      float mx = fmaxf(ca0[r], ca1[r]);
#pragma unroll
      for (int d = 1; d < 16; d <<= 1) mx = fmaxf(mx, __shfl_xor(mx, d));
      const float mnew = fmaxf(m_r[r], mx);
      float p0, p1, al;
      if (mnew == -__builtin_inff()) {    // whole-row-invalid tile: no-op
        p0 = 0.f; p1 = 0.f; al = 1.f;
      } else {
        al = __expf(m_r[r] - mnew);       // exp(-inf)=0 on first valid tile
        p0 = __expf(ca0[r] - mnew);
        p1 = __expf(ca1[r] - mnew);
      }
      float rs = p0 + p1;
#pragma unroll
      for (int d = 1; d < 16; d <<= 1) rs += __shfl_xor(rs, d);
      m_r[r] = mnew;
      l_r[r] = l_r[r] * al + rs;
      alpha[r] = al;
      Pl[w][lgrp * 4 + r][lrow]      = (bf16)p0;
      Pl[w][lgrp * 4 + r][lrow + 16] = (bf16)p1;
    }
#pragma unroll
    for (int dt = 0; dt < 8; ++dt) {
      o[dt][0] *= alpha[0]; o[dt][1] *= alpha[1];
      o[dt][2] *= alpha[2]; o[dt][3] *= alpha[3];
    }
    // wave-local LDS fence (no __syncthreads: waves have divergent trip counts)
    asm volatile("s_waitcnt lgkmcnt(0)" ::: "memory");
    bf16x8 pa = *(const bf16x8*)(&Pl[w][lrow][lgrp * 8]);
#pragma unroll
    for (int dt = 0; dt < 8; ++dt) {
      bf16x8 bv = *(const bf16x8*)(Vb + (size_t)(dt * 16 + lrow) * T_ + j0 + lgrp * 8);
      o[dt] = __builtin_amdgcn_mfma_f32_16x16x32_bf16(pa, bv, o[dt], 0, 0, 0);
    }
  }
  // epilogue: concat layout [b*T + t][hh*D + d] -> GEMM-ready [4096][1024]
#pragma unroll
  for (int dt = 0; dt < 8; ++dt)
#pragma unroll
    for (int r = 0; r < 4; ++r) {
      const int i = qb + lgrp * 4 + r;
      attno[(size_t)(b * T_ + i) * (H_ * D_) + hh * D_ + dt * 16 + lrow] =
          (bf16)(o[dt][r] / l_r[r]);
    }
}

// ---------------------------------------------------------------------------
// bf16 GEMM, m97 structure: BM x 128 tile, BK=64, 4 waves (2x2), each wave
// (BM/2) x 64, MF = BM/32 m-frags.  global_load_lds width 16, single LDS
// buffer, 2 barriers/K-step.  C[m][n] = sum_k A[m][k] * Bt[n][k].
// EPI: 0 = bf16 store; 1 = fp32 store + fp32 residual.
// R4: down @BM=128 grid 256 = 1 block/CU: 90us, Occ 10.5%, Mfma 14.6%.
// R7: down @BM=64 grid 512 = 2 blocks/CU: 75us, Occ 20.1%, Mfma 18% --
// occupancy mechanism confirmed (exactly 2x) but per-block efficiency drops
// (bank conflicts 1.26e7->1.89e7, MFMA:read 8:6 vs 16:8).  Within the
// 2-phase structure this is near the local optimum; next step = 8-phase.
// T2 swizzle still deferred: NULL on 2-phase structure (m228d/m252).
// ---------------------------------------------------------------------------
template <int EPI, int BM>
__global__ __launch_bounds__(256) void gemm_bt_kernel(
    const bf16* __restrict__ A, const bf16* __restrict__ Bt,
    int N, int K,
    bf16* __restrict__ outb, float* __restrict__ outf,
    const float* __restrict__ residf) {
  constexpr int MF = BM / 32;                    // m-frags per wave
  __shared__ bf16 sA[BM][64];
  __shared__ bf16 sB[128][64];
  const int bm = blockIdx.y, bn = blockIdx.x;
  const int tid = threadIdx.x, w = tid >> 6, lane = tid & 63;
  const int wr = w >> 1, wc = w & 1;
  const int lrow = lane & 15, lgrp = lane >> 4;

  const bf16* Ab = A + (size_t)(bm * BM) * K;
  const bf16* Bb = Bt + (size_t)(bn * 128) * K;

  const f32x4 fz = {0.f, 0.f, 0.f, 0.f};
  f32x4 acc[MF][4];
#pragma unroll
  for (int m = 0; m < MF; ++m)
#pragma unroll
    for (int n = 0; n < 4; ++n) acc[m][n] = fz;

  const int stg_row = lane >> 3;                 // 0..7 within a wave's 8 rows
  const int stg_col = (lane & 7) * 8;            // elements (16B)

  for (int k0 = 0; k0 < K; k0 += 64) {
    __syncthreads();                             // readers of prev tile done
#pragma unroll
    for (int c = 0; c < MF; ++c) {               // A: BM rows, 32 rows/pass
      const int r = c * 32 + w * 8;
      gload_lds16(Ab + (size_t)(r + stg_row) * K + k0 + stg_col, &sA[r][0]);
    }
#pragma unroll
    for (int c = 0; c < 4; ++c) {                // B: 128 rows
      const int r = c * 32 + w * 8;
      gload_lds16(Bb + (size_t)(r + stg_row) * K + k0 + stg_col, &sB[r][0]);
    }
    __syncthreads();                             // drains vmcnt(0) first
#pragma unroll
    for (int kk = 0; kk < 2; ++kk) {
      bf16x8 af[MF], bfr[4];
#pragma unroll
      for (int m = 0; m < MF; ++m)
        af[m] = *(const bf16x8*)(&sA[wr * (BM / 2) + m * 16 + lrow][kk * 32 + lgrp * 8]);
#pragma unroll
      for (int n = 0; n < 4; ++n)
        bfr[n] = *(const bf16x8*)(&sB[wc * 64 + n * 16 + lrow][kk * 32 + lgrp * 8]);
#pragma unroll
      for (int m = 0; m < MF; ++m)
#pragma unroll
        for (int n = 0; n < 4; ++n)
          acc[m][n] = __builtin_amdgcn_mfma_f32_16x16x32_bf16(af[m], bfr[n], acc[m][n], 0, 0, 0);
    }
  }

#pragma unroll
  for (int m = 0; m < MF; ++m) {
    const int row0 = bm * BM + wr * (BM / 2) + m * 16 + lgrp * 4;
#pragma unroll
    for (int n = 0; n < 4; ++n) {
      const int col = bn * 128 + wc * 64 + n * 16 + lrow;
#pragma unroll
      for (int r = 0; r < 4; ++r) {
        const size_t idx = (size_t)(row0 + r) * N + col;
        const float v = acc[m][n][r];
        if (EPI == 0) {
          outb[idx] = (bf16)v;
        } else {
          outf[idx] = v + residf[idx];
        }
      }
    }
  }
}

// ---------------------------------------------------------------------------
// Fused gate+up GEMM with silu combine (R7).  hmid = silu(h2@Wg) * (h2@Wu).
// Replaces two 128x128 GEMMs + a 64 MB gbuf round-trip.  One block stages
// the A-tile ONCE for both panels; per kk: 16 MFMA : 8 ds_read_b128 (the
// proven m97 ratio).  BM=128, BN=64 per panel; grid (64,32)=2048 blocks;
// LDS 32 KB; silu sees the fp32 accumulator (slightly better than EPI-2's
// bf16-rounded gbuf read).
// Wgu layout: gate rows [0,4096), up rows [4096,8192), both [.][1024] B^T.
// ---------------------------------------------------------------------------
__global__ __launch_bounds__(256) void fused_gateup_kernel(
    const bf16* __restrict__ A,        // h2 [4096][1024]
    const bf16* __restrict__ Wgu,      // [8192][1024]
    bf16* __restrict__ hmid) {         // [4096][4096]
  __shared__ bf16 sA[128][64];
  __shared__ bf16 sBg[64][64];
  __shared__ bf16 sBu[64][64];
  const int bm = blockIdx.y, bn = blockIdx.x;   // bm 0..31, bn 0..63
  const int tid = threadIdx.x, w = tid >> 6, lane = tid & 63;
  const int wr = w >> 1, wc = w & 1;
  const int lrow = lane & 15, lgrp = lane >> 4;

  const bf16* Ab = A + (size_t)(bm * 128) * 1024;
  const bf16* Bg = Wgu + (size_t)(bn * 64) * 1024;
  const bf16* Bu = Wgu + (size_t)(4096 + bn * 64) * 1024;

  const f32x4 fz = {0.f, 0.f, 0.f, 0.f};
  f32x4 accg[4][2], accu[4][2];
#pragma unroll
  for (int m = 0; m < 4; ++m)
#pragma unroll
    for (int n = 0; n < 2; ++n) { accg[m][n] = fz; accu[m][n] = fz; }

  const int stg_row = lane >> 3;                 // 0..7
  const int stg_col = (lane & 7) * 8;            // 16B

  for (int k0 = 0; k0 < 1024; k0 += 64) {
    __syncthreads();
#pragma unroll
    for (int c = 0; c < 4; ++c) {                // A: 128 rows
      const int r = c * 32 + w * 8;
      gload_lds16(Ab + (size_t)(r + stg_row) * 1024 + k0 + stg_col, &sA[r][0]);
    }
#pragma unroll
    for (int c = 0; c < 2; ++c) {                // Bg, Bu: 64 rows each
      const int r = c * 32 + w * 8;
      gload_lds16(Bg + (size_t)(r + stg_row) * 1024 + k0 + stg_col, &sBg[r][0]);
      gload_lds16(Bu + (size_t)(r + stg_row) * 1024 + k0 + stg_col, &sBu[r][0]);
    }
    __syncthreads();                             // drains vmcnt(0) first
#pragma unroll
    for (int kk = 0; kk < 2; ++kk) {
      bf16x8 af[4], bg[2], bu[2];
#pragma unroll
      for (int m = 0; m < 4; ++m)
        af[m] = *(const bf16x8*)(&sA[wr * 64 + m * 16 + lrow][kk * 32 + lgrp * 8]);
#pragma unroll
      for (int n = 0; n < 2; ++n) {
        bg[n] = *(const bf16x8*)(&sBg[wc * 32 + n * 16 + lrow][kk * 32 + lgrp * 8]);
        bu[n] = *(const bf16x8*)(&sBu[wc * 32 + n * 16 + lrow][kk * 32 + lgrp * 8]);
      }
#pragma unroll
      for (int m = 0; m < 4; ++m)
#pragma unroll
        for (int n = 0; n < 2; ++n) {
          accg[m][n] = __builtin_amdgcn_mfma_f32_16x16x32_bf16(af[m], bg[n], accg[m][n], 0, 0, 0);
          accu[m][n] = __builtin_amdgcn_mfma_f32_16x16x32_bf16(af[m], bu[n], accu[m][n], 0, 0, 0);
        }
    }
  }

#pragma unroll
  for (int m = 0; m < 4; ++m) {
    const int row0 = bm * 128 + wr * 64 + m * 16 + lgrp * 4;
#pragma unroll
    for (int n = 0; n < 2; ++n) {
      const int col = bn * 64 + wc * 32 + n * 16 + lrow;
#pragma unroll
      for (int r = 0; r < 4; ++r) {
        const float g = accg[m][n][r];
        const float u = accu[m][n][r];
        const float sg = g / (1.f + __expf(-g));
        hmid[(size_t)(row0 + r) * HID_ + col] = (bf16)(sg * u);
      }
    }
  }
}

// ---------------------------------------------------------------------------
extern "C" void kernel_launch(void* const* d_in, const int* in_sizes, int n_in,
                              void* d_out, int out_size, void* d_ws, size_t ws_size,
                              hipStream_t stream) {
  const float* x      = (const float*)d_in[0];
  const float* qk_w   = (const float*)d_in[1];
  const float* kk_w   = (const float*)d_in[2];
  const float* vk_w   = (const float*)d_in[3];
  const float* ok_w   = (const float*)d_in[4];
  const float* ascale = (const float*)d_in[5];
  const float* mscale = (const float*)d_in[6];
  const float* gk_w   = (const float*)d_in[7];
  const float* uk_w   = (const float*)d_in[8];
  const float* dk_w   = (const float*)d_in[9];
  float* out = (float*)d_out;

  char* p = (char*)d_ws;
  auto alloc = [&](size_t bytes) {
    char* r = p;
    p += (bytes + 255) & ~(size_t)255;
    return r;
  };
  bf16*  Wqkv = (bf16*)alloc((size_t)2048 * 1024 * 2);   // [N=2048][K=1024] B^T
  bf16*  Wo   = (bf16*)alloc((size_t)1024 * 1024 * 2);   // [1024][1024]
  bf16*  Wgu  = (bf16*)alloc((size_t)8192 * 1024 * 2);   // gate rows 0..4095, up 4096..8191
  bf16*  Wdn  = (bf16*)alloc((size_t)1024 * 4096 * 2);   // [1024][4096]
  float* ct   = (float*)alloc((size_t)T_ * 64 * 4);
  float* st   = (float*)alloc((size_t)T_ * 64 * 4);
  bf16*  h1   = (bf16*)alloc((size_t)NTOK * C_ * 2);
  bf16*  qkv  = (bf16*)alloc((size_t)NTOK * 2048 * 2);
  bf16*  Qr   = (bf16*)alloc((size_t)B_ * H_ * T_ * D_ * 2);
  bf16*  Kr   = (bf16*)alloc((size_t)B_ * KV_ * T_ * D_ * 2);
  bf16*  Vt   = (bf16*)alloc((size_t)B_ * KV_ * T_ * D_ * 2);
  bf16*  attno= (bf16*)alloc((size_t)NTOK * 1024 * 2);
  float* x2   = (float*)alloc((size_t)NTOK * C_ * 4);
  bf16*  h2   = (bf16*)alloc((size_t)NTOK * C_ * 2);
  bf16*  hmid = (bf16*)alloc((size_t)NTOK * HID_ * 2);
  (void)ws_size; (void)in_sizes; (void)n_in; (void)out_size;

  const dim3 tb(32, 8);

  // RoPE table + weight cast/transpose (independent of activations)
  rope_table_kernel<<<dim3((T_ * 64 + 255) / 256), dim3(256), 0, stream>>>(ct, st);
  transpose_cast_kernel<<<dim3(32, 32), tb, 0, stream>>>(qk_w, 1024, Wqkv, 1024, 1024, 1024);
  transpose_cast_kernel<<<dim3(16, 32), tb, 0, stream>>>(kk_w, 512, Wqkv + (size_t)1024 * 1024, 1024, 1024, 512);
  transpose_cast_kernel<<<dim3(16, 32), tb, 0, stream>>>(vk_w, 512, Wqkv + (size_t)1536 * 1024, 1024, 1024, 512);
  transpose_cast_kernel<<<dim3(32, 32), tb, 0, stream>>>(ok_w, 1024, Wo, 1024, 1024, 1024);
  transpose_cast_kernel<<<dim3(128, 32), tb, 0, stream>>>(gk_w, 4096, Wgu, 1024, 1024, 4096);
  transpose_cast_kernel<<<dim3(128, 32), tb, 0, stream>>>(uk_w, 4096, Wgu + (size_t)4096 * 1024, 1024, 1024, 4096);
  transpose_cast_kernel<<<dim3(32, 128), tb, 0, stream>>>(dk_w, 1024, Wdn, 4096, 4096, 1024);

  // Attention branch
  rmsnorm_kernel<<<dim3(NTOK), dim3(256), 0, stream>>>(x, ascale, h1);
  gemm_bt_kernel<0, 128><<<dim3(16, 32), dim3(256), 0, stream>>>(h1, Wqkv, 2048, 1024, qkv, nullptr, nullptr);
  rope_apply_kernel<<<dim3(NTOK), dim3(256), 0, stream>>>(qkv, ct, st, Qr, Kr);
  transpose_v_kernel<<<dim3(64, 4, 8), tb, 0, stream>>>(qkv, Vt);
  attn_kernel<<<dim3(32, 8, 2), dim3(256), 0, stream>>>(Qr, Kr, Vt, attno);
  // out-proj: BM=64 -> grid (8,64)=512 blocks = 2 blocks/CU
  gemm_bt_kernel<1, 64><<<dim3(8, 64), dim3(256), 0, stream>>>(attno, Wo, 1024, 1024, nullptr, x2, x);

  // MLP branch
  rmsnorm_kernel<<<dim3(NTOK), dim3(256), 0, stream>>>(x2, mscale, h2);
  // fused gate+up with silu combine (replaces two GEMMs + gbuf round-trip)
  fused_gateup_kernel<<<dim3(64, 32), dim3(256), 0, stream>>>(h2, Wgu, hmid);
  // down: BM=64 -> grid (8,64)=512 blocks = 2 blocks/CU
  gemm_bt_kernel<1, 64><<<dim3(8, 64), dim3(256), 0, stream>>>(hmid, Wdn, 1024, 4096, nullptr, out, x2);
}

// Round 9
// 412.433 us; speedup vs baseline: 1.1450x; 1.0922x over previous
//
#include <hip/hip_runtime.h>
#include <hip/hip_bf16.h>
#include <math.h>

// Problem constants (from reference)
#define B_   2
#define T_   2048
#define C_   1024
#define H_   8
#define KV_  4
#define D_   128
#define WIN_ 512
#define HID_ 4096
#define NTOK (B_*T_)          // 4096 tokens
#define QK_SCALE 0.08838834764831845f   // rsqrt(128)

typedef __bf16 bf16;
typedef __attribute__((ext_vector_type(8))) __bf16 bf16x8;   // MFMA A/B frag (4 VGPR)
typedef __attribute__((ext_vector_type(4))) __bf16 bf16x4;
typedef __attribute__((ext_vector_type(4))) float  f32x4;    // MFMA C/D frag

#define AS1 __attribute__((address_space(1)))
#define AS3 __attribute__((address_space(3)))

// async global->LDS, 16B/lane. LDS dest is wave-uniform base + lane*16 (m97 pattern).
__device__ __forceinline__ void gload_lds16(const bf16* g, bf16* l) {
  __builtin_amdgcn_global_load_lds((const AS1 void*)g, (AS3 void*)l, 16, 0, 0);
}

// ---------------------------------------------------------------------------
// Weight cast+transpose: dst[n][k] = (bf16)src[k][n].  B^T layout so GEMM
// B-fragments are 8-contiguous-k b128 reads (layout proven by m92/m97).
// grid: (N/32, K/32), block (32,8)
// ---------------------------------------------------------------------------
__global__ void transpose_cast_kernel(const float* __restrict__ src, int ldsrc,
                                      bf16* __restrict__ dst, int lddst,
                                      int K, int N) {
  __shared__ float tile[32][33];
  const int n0 = blockIdx.x * 32, k0 = blockIdx.y * 32;
  const int tx = threadIdx.x, ty = threadIdx.y;
#pragma unroll
  for (int i = 0; i < 32; i += 8)
    tile[ty + i][tx] = src[(size_t)(k0 + ty + i) * ldsrc + n0 + tx];
  __syncthreads();
#pragma unroll
  for (int i = 0; i < 32; i += 8)
    dst[(size_t)(n0 + ty + i) * lddst + k0 + tx] = (bf16)tile[tx][ty + i];
}

// V transpose: vt[(b*KV+h)*D + d][t] = qkv[b*T+t][1536 + h*128 + d]
// grid: (T/32, D/32, B*KV), block (32,8)
__global__ void transpose_v_kernel(const bf16* __restrict__ qkv, bf16* __restrict__ vt) {
  __shared__ bf16 tile[32][33];
  const int bh = blockIdx.z, b = bh >> 2, h = bh & 3;
  const int t0 = blockIdx.x * 32, d0 = blockIdx.y * 32;
  const int tx = threadIdx.x, ty = threadIdx.y;
#pragma unroll
  for (int i = 0; i < 32; i += 8)
    tile[ty + i][tx] = qkv[(size_t)(b * T_ + t0 + ty + i) * 2048 + 1536 + h * 128 + d0 + tx];
  __syncthreads();
#pragma unroll
  for (int i = 0; i < 32; i += 8)
    vt[(size_t)((b * KV_ + h) * D_ + d0 + ty + i) * T_ + t0 + tx] = tile[tx][ty + i];
}

// ---------------------------------------------------------------------------
// RoPE sin/cos table: [T][64] each (the two D/2 halves share angles)
// ---------------------------------------------------------------------------
__global__ void rope_table_kernel(float* __restrict__ ct, float* __restrict__ st) {
  const int idx = blockIdx.x * 256 + threadIdx.x;
  if (idx >= T_ * 64) return;
  const int t = idx >> 6, i = idx & 63;
  const float inv = __expf(-(float)i * (1.0f / 64.0f) * logf(10000.0f));
  const float a = (float)t * inv;
  ct[idx] = cosf(a);
  st[idx] = sinf(a);
}

// ---------------------------------------------------------------------------
// RMSNorm (fp32 in) -> bf16 out.  One block per row, 256 threads * float4.
// ---------------------------------------------------------------------------
__global__ __launch_bounds__(256) void rmsnorm_kernel(const float* __restrict__ x,
                                                      const float* __restrict__ scale,
                                                      bf16* __restrict__ out) {
  const int row = blockIdx.x;
  const float* xr = x + (size_t)row * C_;
  const int tid = threadIdx.x;
  float4 v = ((const float4*)xr)[tid];
  float ss = v.x * v.x + v.y * v.y + v.z * v.z + v.w * v.w;
#pragma unroll
  for (int o = 32; o > 0; o >>= 1) ss += __shfl_down(ss, o);
  __shared__ float part[4];
  __shared__ float total;
  if ((tid & 63) == 0) part[tid >> 6] = ss;
  __syncthreads();
  if (tid == 0) total = part[0] + part[1] + part[2] + part[3];
  __syncthreads();
  const float r = rsqrtf(total * (1.0f / C_) + 1e-6f);
  float4 sc = ((const float4*)scale)[tid];
  bf16x4 o4;
  o4[0] = (bf16)(v.x * r * (1.f + sc.x));
  o4[1] = (bf16)(v.y * r * (1.f + sc.y));
  o4[2] = (bf16)(v.z * r * (1.f + sc.z));
  o4[3] = (bf16)(v.w * r * (1.f + sc.w));
  *(bf16x4*)(out + (size_t)row * C_ + tid * 4) = o4;
}

// ---------------------------------------------------------------------------
// RoPE apply + scatter into attention layouts.
// qkv row layout: cols [0,1024) q heads (hh = r*KV+h), [1024,1536) k, rest v.
// Qr[b][hh][t][d] (scaled by rsqrt(D)), Kr[b][h][t][d].  V handled separately.
// grid: NTOK blocks, 256 threads (4 waves x 3 head-chunks, lane = rope pair idx)
// ---------------------------------------------------------------------------
__global__ __launch_bounds__(256) void rope_apply_kernel(const bf16* __restrict__ qkv,
                                                         const float* __restrict__ ct,
                                                         const float* __restrict__ st,
                                                         bf16* __restrict__ Qr,
                                                         bf16* __restrict__ Kr) {
  const int row = blockIdx.x;            // b*T + t
  const int b = row >> 11, t = row & (T_ - 1);
  const int w = threadIdx.x >> 6, lane = threadIdx.x & 63;
  const float c = ct[t * 64 + lane], s = st[t * 64 + lane];
#pragma unroll
  for (int q = 0; q < 3; ++q) {
    const int ch = w * 3 + q;            // 0..11  (8 q-heads, 4 k-heads)
    const bf16* src = qkv + (size_t)row * 2048 + ch * 128;
    float x1 = (float)src[lane], x2 = (float)src[lane + 64];
    float o1 = x1 * c - x2 * s;
    float o2 = x2 * c + x1 * s;
    bf16* dst;
    if (ch < 8) {
      o1 *= QK_SCALE; o2 *= QK_SCALE;
      dst = Qr + (size_t)((b * H_ + ch) * T_ + t) * D_;
    } else {
      dst = Kr + (size_t)((b * KV_ + (ch - 8)) * T_ + t) * D_;
    }
    dst[lane] = (bf16)o1;
    dst[lane + 64] = (bf16)o2;
  }
}

// ---------------------------------------------------------------------------
// Flash attention, sliding window + causal + softcap(50).
// grid (T/64, H, B); 4 waves/block, each wave owns 16 q-rows independently
// (no barriers -- waves have different KV ranges).  KV tiles of 32.
// kv head = hh % KV (reference reshapes q_kernel to (C,R,KV,D): hh = r*KV+h).
// Pl rows padded to 40 elements (80B = 5x16B, so b128 reads stay aligned).
// Edge case (audited r3): whole-row-invalid first tile -> mnew==-inf no-op
// branch REQUIRED (prevents exp(-inf-(-inf))=NaN poisoning l_r).
// ---------------------------------------------------------------------------
__global__ __launch_bounds__(256) void attn_kernel(const bf16* __restrict__ Qr,
                                                   const bf16* __restrict__ Kr,
                                                   const bf16* __restrict__ Vt,
                                                   bf16* __restrict__ attno) {
  __shared__ bf16 Pl[4][16][40];         // per-wave P tile (i x j'), padded
  const int qt = blockIdx.x, hh = blockIdx.y, b = blockIdx.z;
  const int h = hh & (KV_ - 1);
  const int w = threadIdx.x >> 6, lane = threadIdx.x & 63;
  const int lrow = lane & 15, lgrp = lane >> 4;
  const int qb = qt * 64 + w * 16;

  const bf16* Qb = Qr + ((size_t)(b * H_ + hh) * T_ + qb + lrow) * D_;
  const bf16* Kb = Kr + (size_t)(b * KV_ + h) * T_ * D_;
  const bf16* Vb = Vt + (size_t)(b * KV_ + h) * D_ * T_;

  bf16x8 aq[4];
#pragma unroll
  for (int dt = 0; dt < 4; ++dt)
    aq[dt] = *(const bf16x8*)(Qb + dt * 32 + lgrp * 8);

  const f32x4 fz = {0.f, 0.f, 0.f, 0.f};
  f32x4 o[8];
#pragma unroll
  for (int i = 0; i < 8; ++i) o[i] = fz;
  float m_r[4], l_r[4];
#pragma unroll
  for (int r = 0; r < 4; ++r) { m_r[r] = -__builtin_inff(); l_r[r] = 0.f; }

  int jlo = qb - (WIN_ - 1); if (jlo < 0) jlo = 0;
  for (int j0 = (jlo & ~31); j0 <= qb + 15; j0 += 32) {
    // S = Q K^T  (two 16x16 col-tiles)
    f32x4 sv0 = fz, sv1 = fz;
#pragma unroll
    for (int dt = 0; dt < 4; ++dt) {
      bf16x8 bk0 = *(const bf16x8*)(Kb + (size_t)(j0 + lrow) * D_ + dt * 32 + lgrp * 8);
      bf16x8 bk1 = *(const bf16x8*)(Kb + (size_t)(j0 + 16 + lrow) * D_ + dt * 32 + lgrp * 8);
      sv0 = __builtin_amdgcn_mfma_f32_16x16x32_bf16(aq[dt], bk0, sv0, 0, 0, 0);
      sv1 = __builtin_amdgcn_mfma_f32_16x16x32_bf16(aq[dt], bk1, sv1, 0, 0, 0);
    }
    // softcap + mask.  C/D layout: col = lane&15, row = (lane>>4)*4 + reg.
    float ca0[4], ca1[4];
    const int c0 = j0 + lrow, c1 = c0 + 16;
#pragma unroll
    for (int r = 0; r < 4; ++r) {
      const int i = qb + lgrp * 4 + r;
      float a0 = 50.f * tanhf(sv0[r] * 0.02f);
      float a1 = 50.f * tanhf(sv1[r] * 0.02f);
      ca0[r] = (c0 <= i && c0 >= i - (WIN_ - 1)) ? a0 : -__builtin_inff();
      ca1[r] = (c1 <= i && c1 >= i - (WIN_ - 1)) ? a1 : -__builtin_inff();
    }
    // online softmax (row-reduce across the 16 lanes of the lane-group)
    float alpha[4];
#pragma unroll
    for (int r = 0; r < 4; ++r) {
      float mx = fmaxf(ca0[r], ca1[r]);
#pragma unroll
      for (int d = 1; d < 16; d <<= 1) mx = fmaxf(mx, __shfl_xor(mx, d));
      const float mnew = fmaxf(m_r[r], mx);
      float p0, p1, al;
      if (mnew == -__builtin_inff()) {    // whole-row-invalid tile: no-op
        p0 = 0.f; p1 = 0.f; al = 1.f;
      } else {
        al = __expf(m_r[r] - mnew);       // exp(-inf)=0 on first valid tile
        p0 = __expf(ca0[r] - mnew);
        p1 = __expf(ca1[r] - mnew);
      }
      float rs = p0 + p1;
#pragma unroll
      for (int d = 1; d < 16; d <<= 1) rs += __shfl_xor(rs, d);
      m_r[r] = mnew;
      l_r[r] = l_r[r] * al + rs;
      alpha[r] = al;
      Pl[w][lgrp * 4 + r][lrow]      = (bf16)p0;
      Pl[w][lgrp * 4 + r][lrow + 16] = (bf16)p1;
    }
#pragma unroll
    for (int dt = 0; dt < 8; ++dt) {
      o[dt][0] *= alpha[0]; o[dt][1] *= alpha[1];
      o[dt][2] *= alpha[2]; o[dt][3] *= alpha[3];
    }
    // wave-local LDS fence (no __syncthreads: waves have divergent trip counts)
    asm volatile("s_waitcnt lgkmcnt(0)" ::: "memory");
    bf16x8 pa = *(const bf16x8*)(&Pl[w][lrow][lgrp * 8]);
#pragma unroll
    for (int dt = 0; dt < 8; ++dt) {
      bf16x8 bv = *(const bf16x8*)(Vb + (size_t)(dt * 16 + lrow) * T_ + j0 + lgrp * 8);
      o[dt] = __builtin_amdgcn_mfma_f32_16x16x32_bf16(pa, bv, o[dt], 0, 0, 0);
    }
  }
  // epilogue: concat layout [b*T + t][hh*D + d] -> GEMM-ready [4096][1024]
#pragma unroll
  for (int dt = 0; dt < 8; ++dt)
#pragma unroll
    for (int r = 0; r < 4; ++r) {
      const int i = qb + lgrp * 4 + r;
      attno[(size_t)(b * T_ + i) * (H_ * D_) + hh * D_ + dt * 16 + lrow] =
          (bf16)(o[dt][r] / l_r[r]);
    }
}

// ---------------------------------------------------------------------------
// bf16 GEMM, m97 structure + R8 both-sides XOR swizzle (rule #21 / m173):
// LDS dest stays linear (gload_lds requires it); the global SOURCE col chunk
// is pre-swizzled (lane&7)^(lane>>3) -- valid because every staged 8-row
// group is 8-row-aligned so row&7 == lane>>3 -- and the ds_read col applies
// the same XOR: chunk' = (kk*4+lgrp) ^ (row&7).  16 lanes then hit 8
// distinct 16B slots covering all 32 banks = 2 lanes/bank = free (m136).
// R8 evidence this matters: SQ_LDS_BANK_CONFLICT ~= 35-41% of wall cycles
// on fused/down (2.5e7 / 1.9e7 per dispatch) -- NOT hidden under the stage
// path at our shapes (unlike m252's null).  Distinguishing experiment:
// conflicts must drop >10x regardless; if time is flat, stage-drain rules
// and the 8-phase port is next.
// EPI: 0 = bf16 store; 1 = fp32 store + fp32 residual.
// ---------------------------------------------------------------------------
template <int EPI, int BM>
__global__ __launch_bounds__(256) void gemm_bt_kernel(
    const bf16* __restrict__ A, const bf16* __restrict__ Bt,
    int N, int K,
    bf16* __restrict__ outb, float* __restrict__ outf,
    const float* __restrict__ residf) {
  constexpr int MF = BM / 32;                    // m-frags per wave
  __shared__ bf16 sA[BM][64];
  __shared__ bf16 sB[128][64];
  const int bm = blockIdx.y, bn = blockIdx.x;
  const int tid = threadIdx.x, w = tid >> 6, lane = tid & 63;
  const int wr = w >> 1, wc = w & 1;
  const int lrow = lane & 15, lgrp = lane >> 4;
  const int swz = lrow & 7;                      // read-side XOR key (=row&7)

  const bf16* Ab = A + (size_t)(bm * BM) * K;
  const bf16* Bb = Bt + (size_t)(bn * 128) * K;

  const f32x4 fz = {0.f, 0.f, 0.f, 0.f};
  f32x4 acc[MF][4];
#pragma unroll
  for (int m = 0; m < MF; ++m)
#pragma unroll
    for (int n = 0; n < 4; ++n) acc[m][n] = fz;

  const int stg_row = lane >> 3;                 // 0..7 within a wave's 8 rows
  const int stg_col = ((lane & 7) ^ (lane >> 3)) * 8;  // inverse-swizzled src

  for (int k0 = 0; k0 < K; k0 += 64) {
    __syncthreads();                             // readers of prev tile done
#pragma unroll
    for (int c = 0; c < MF; ++c) {               // A: BM rows, 32 rows/pass
      const int r = c * 32 + w * 8;              // 8-row aligned (swizzle req)
      gload_lds16(Ab + (size_t)(r + stg_row) * K + k0 + stg_col, &sA[r][0]);
    }
#pragma unroll
    for (int c = 0; c < 4; ++c) {                // B: 128 rows
      const int r = c * 32 + w * 8;
      gload_lds16(Bb + (size_t)(r + stg_row) * K + k0 + stg_col, &sB[r][0]);
    }
    __syncthreads();                             // drains vmcnt(0) first
#pragma unroll
    for (int kk = 0; kk < 2; ++kk) {
      const int rc = ((kk * 4 + lgrp) ^ swz) * 8;  // swizzled read col
      bf16x8 af[MF], bfr[4];
#pragma unroll
      for (int m = 0; m < MF; ++m)
        af[m] = *(const bf16x8*)(&sA[wr * (BM / 2) + m * 16 + lrow][rc]);
#pragma unroll
      for (int n = 0; n < 4; ++n)
        bfr[n] = *(const bf16x8*)(&sB[wc * 64 + n * 16 + lrow][rc]);
#pragma unroll
      for (int m = 0; m < MF; ++m)
#pragma unroll
        for (int n = 0; n < 4; ++n)
          acc[m][n] = __builtin_amdgcn_mfma_f32_16x16x32_bf16(af[m], bfr[n], acc[m][n], 0, 0, 0);
    }
  }

#pragma unroll
  for (int m = 0; m < MF; ++m) {
    const int row0 = bm * BM + wr * (BM / 2) + m * 16 + lgrp * 4;
#pragma unroll
    for (int n = 0; n < 4; ++n) {
      const int col = bn * 128 + wc * 64 + n * 16 + lrow;
#pragma unroll
      for (int r = 0; r < 4; ++r) {
        const size_t idx = (size_t)(row0 + r) * N + col;
        const float v = acc[m][n][r];
        if (EPI == 0) {
          outb[idx] = (bf16)v;
        } else {
          outf[idx] = v + residf[idx];
        }
      }
    }
  }
}

// ---------------------------------------------------------------------------
// Fused gate+up GEMM with silu combine.  hmid = silu(h2@Wg) * (h2@Wu).
// R8: 117.7us, Mfma 24%, VALU 33%, HBM 10%, conflicts 2.5e7 (~35% of
// cycles) -> same both-sides XOR swizzle applied here (see gemm_bt note).
// Wgu layout: gate rows [0,4096), up rows [4096,8192), both [.][1024] B^T.
// ---------------------------------------------------------------------------
__global__ __launch_bounds__(256) void fused_gateup_kernel(
    const bf16* __restrict__ A,        // h2 [4096][1024]
    const bf16* __restrict__ Wgu,      // [8192][1024]
    bf16* __restrict__ hmid) {         // [4096][4096]
  __shared__ bf16 sA[128][64];
  __shared__ bf16 sBg[64][64];
  __shared__ bf16 sBu[64][64];
  const int bm = blockIdx.y, bn = blockIdx.x;   // bm 0..31, bn 0..63
  const int tid = threadIdx.x, w = tid >> 6, lane = tid & 63;
  const int wr = w >> 1, wc = w & 1;
  const int lrow = lane & 15, lgrp = lane >> 4;
  const int swz = lrow & 7;

  const bf16* Ab = A + (size_t)(bm * 128) * 1024;
  const bf16* Bg = Wgu + (size_t)(bn * 64) * 1024;
  const bf16* Bu = Wgu + (size_t)(4096 + bn * 64) * 1024;

  const f32x4 fz = {0.f, 0.f, 0.f, 0.f};
  f32x4 accg[4][2], accu[4][2];
#pragma unroll
  for (int m = 0; m < 4; ++m)
#pragma unroll
    for (int n = 0; n < 2; ++n) { accg[m][n] = fz; accu[m][n] = fz; }

  const int stg_row = lane >> 3;                 // 0..7
  const int stg_col = ((lane & 7) ^ (lane >> 3)) * 8;  // inverse-swizzled src

  for (int k0 = 0; k0 < 1024; k0 += 64) {
    __syncthreads();
#pragma unroll
    for (int c = 0; c < 4; ++c) {                // A: 128 rows
      const int r = c * 32 + w * 8;
      gload_lds16(Ab + (size_t)(r + stg_row) * 1024 + k0 + stg_col, &sA[r][0]);
    }
#pragma unroll
    for (int c = 0; c < 2; ++c) {                // Bg, Bu: 64 rows each
      const int r = c * 32 + w * 8;
      gload_lds16(Bg + (size_t)(r + stg_row) * 1024 + k0 + stg_col, &sBg[r][0]);
      gload_lds16(Bu + (size_t)(r + stg_row) * 1024 + k0 + stg_col, &sBu[r][0]);
    }
    __syncthreads();                             // drains vmcnt(0) first
#pragma unroll
    for (int kk = 0; kk < 2; ++kk) {
      const int rc = ((kk * 4 + lgrp) ^ swz) * 8;
      bf16x8 af[4], bg[2], bu[2];
#pragma unroll
      for (int m = 0; m < 4; ++m)
        af[m] = *(const bf16x8*)(&sA[wr * 64 + m * 16 + lrow][rc]);
#pragma unroll
      for (int n = 0; n < 2; ++n) {
        bg[n] = *(const bf16x8*)(&sBg[wc * 32 + n * 16 + lrow][rc]);
        bu[n] = *(const bf16x8*)(&sBu[wc * 32 + n * 16 + lrow][rc]);
      }
#pragma unroll
      for (int m = 0; m < 4; ++m)
#pragma unroll
        for (int n = 0; n < 2; ++n) {
          accg[m][n] = __builtin_amdgcn_mfma_f32_16x16x32_bf16(af[m], bg[n], accg[m][n], 0, 0, 0);
          accu[m][n] = __builtin_amdgcn_mfma_f32_16x16x32_bf16(af[m], bu[n], accu[m][n], 0, 0, 0);
        }
    }
  }

#pragma unroll
  for (int m = 0; m < 4; ++m) {
    const int row0 = bm * 128 + wr * 64 + m * 16 + lgrp * 4;
#pragma unroll
    for (int n = 0; n < 2; ++n) {
      const int col = bn * 64 + wc * 32 + n * 16 + lrow;
#pragma unroll
      for (int r = 0; r < 4; ++r) {
        const float g = accg[m][n][r];
        const float u = accu[m][n][r];
        const float sg = g / (1.f + __expf(-g));
        hmid[(size_t)(row0 + r) * HID_ + col] = (bf16)(sg * u);
      }
    }
  }
}

// ---------------------------------------------------------------------------
extern "C" void kernel_launch(void* const* d_in, const int* in_sizes, int n_in,
                              void* d_out, int out_size, void* d_ws, size_t ws_size,
                              hipStream_t stream) {
  const float* x      = (const float*)d_in[0];
  const float* qk_w   = (const float*)d_in[1];
  const float* kk_w   = (const float*)d_in[2];
  const float* vk_w   = (const float*)d_in[3];
  const float* ok_w   = (const float*)d_in[4];
  const float* ascale = (const float*)d_in[5];
  const float* mscale = (const float*)d_in[6];
  const float* gk_w   = (const float*)d_in[7];
  const float* uk_w   = (const float*)d_in[8];
  const float* dk_w   = (const float*)d_in[9];
  float* out = (float*)d_out;

  char* p = (char*)d_ws;
  auto alloc = [&](size_t bytes) {
    char* r = p;
    p += (bytes + 255) & ~(size_t)255;
    return r;
  };
  bf16*  Wqkv = (bf16*)alloc((size_t)2048 * 1024 * 2);   // [N=2048][K=1024] B^T
  bf16*  Wo   = (bf16*)alloc((size_t)1024 * 1024 * 2);   // [1024][1024]
  bf16*  Wgu  = (bf16*)alloc((size_t)8192 * 1024 * 2);   // gate rows 0..4095, up 4096..8191
  bf16*  Wdn  = (bf16*)alloc((size_t)1024 * 4096 * 2);   // [1024][4096]
  float* ct   = (float*)alloc((size_t)T_ * 64 * 4);
  float* st   = (float*)alloc((size_t)T_ * 64 * 4);
  bf16*  h1   = (bf16*)alloc((size_t)NTOK * C_ * 2);
  bf16*  qkv  = (bf16*)alloc((size_t)NTOK * 2048 * 2);
  bf16*  Qr   = (bf16*)alloc((size_t)B_ * H_ * T_ * D_ * 2);
  bf16*  Kr   = (bf16*)alloc((size_t)B_ * KV_ * T_ * D_ * 2);
  bf16*  Vt   = (bf16*)alloc((size_t)B_ * KV_ * T_ * D_ * 2);
  bf16*  attno= (bf16*)alloc((size_t)NTOK * 1024 * 2);
  float* x2   = (float*)alloc((size_t)NTOK * C_ * 4);
  bf16*  h2   = (bf16*)alloc((size_t)NTOK * C_ * 2);
  bf16*  hmid = (bf16*)alloc((size_t)NTOK * HID_ * 2);
  (void)ws_size; (void)in_sizes; (void)n_in; (void)out_size;

  const dim3 tb(32, 8);

  // RoPE table + weight cast/transpose (independent of activations)
  rope_table_kernel<<<dim3((T_ * 64 + 255) / 256), dim3(256), 0, stream>>>(ct, st);
  transpose_cast_kernel<<<dim3(32, 32), tb, 0, stream>>>(qk_w, 1024, Wqkv, 1024, 1024, 1024);
  transpose_cast_kernel<<<dim3(16, 32), tb, 0, stream>>>(kk_w, 512, Wqkv + (size_t)1024 * 1024, 1024, 1024, 512);
  transpose_cast_kernel<<<dim3(16, 32), tb, 0, stream>>>(vk_w, 512, Wqkv + (size_t)1536 * 1024, 1024, 1024, 512);
  transpose_cast_kernel<<<dim3(32, 32), tb, 0, stream>>>(ok_w, 1024, Wo, 1024, 1024, 1024);
  transpose_cast_kernel<<<dim3(128, 32), tb, 0, stream>>>(gk_w, 4096, Wgu, 1024, 1024, 4096);
  transpose_cast_kernel<<<dim3(128, 32), tb, 0, stream>>>(uk_w, 4096, Wgu + (size_t)4096 * 1024, 1024, 1024, 4096);
  transpose_cast_kernel<<<dim3(32, 128), tb, 0, stream>>>(dk_w, 1024, Wdn, 4096, 4096, 1024);

  // Attention branch
  rmsnorm_kernel<<<dim3(NTOK), dim3(256), 0, stream>>>(x, ascale, h1);
  gemm_bt_kernel<0, 128><<<dim3(16, 32), dim3(256), 0, stream>>>(h1, Wqkv, 2048, 1024, qkv, nullptr, nullptr);
  rope_apply_kernel<<<dim3(NTOK), dim3(256), 0, stream>>>(qkv, ct, st, Qr, Kr);
  transpose_v_kernel<<<dim3(64, 4, 8), tb, 0, stream>>>(qkv, Vt);
  attn_kernel<<<dim3(32, 8, 2), dim3(256), 0, stream>>>(Qr, Kr, Vt, attno);
  // out-proj: BM=64 -> grid (8,64)=512 blocks = 2 blocks/CU
  gemm_bt_kernel<1, 64><<<dim3(8, 64), dim3(256), 0, stream>>>(attno, Wo, 1024, 1024, nullptr, x2, x);

  // MLP branch
  rmsnorm_kernel<<<dim3(NTOK), dim3(256), 0, stream>>>(x2, mscale, h2);
  // fused gate+up with silu combine (replaces two GEMMs + gbuf round-trip)
  fused_gateup_kernel<<<dim3(64, 32), dim3(256), 0, stream>>>(h2, Wgu, hmid);
  // down: BM=64 -> grid (8,64)=512 blocks = 2 blocks/CU
  gemm_bt_kernel<1, 64><<<dim3(8, 64), dim3(256), 0, stream>>>(hmid, Wdn, 1024, 4096, nullptr, out, x2);
}

// Round 11
// 410.177 us; speedup vs baseline: 1.1513x; 1.0055x over previous
//
#include <hip/hip_runtime.h>
#include <hip/hip_bf16.h>
#include <math.h>

// Problem constants (from reference)
#define B_   2
#define T_   2048
#define C_   1024
#define H_   8
#define KV_  4
#define D_   128
#define WIN_ 512
#define HID_ 4096
#define NTOK (B_*T_)          // 4096 tokens
#define QK_SCALE 0.08838834764831845f   // rsqrt(128)

typedef __bf16 bf16;
typedef __attribute__((ext_vector_type(8))) __bf16 bf16x8;   // MFMA A/B frag (4 VGPR)
typedef __attribute__((ext_vector_type(4))) __bf16 bf16x4;
typedef __attribute__((ext_vector_type(4))) float  f32x4;    // MFMA C/D frag

#define AS1 __attribute__((address_space(1)))
#define AS3 __attribute__((address_space(3)))

// async global->LDS, 16B/lane. LDS dest is wave-uniform base + lane*16 (m97 pattern).
__device__ __forceinline__ void gload_lds16(const bf16* g, bf16* l) {
  __builtin_amdgcn_global_load_lds((const AS1 void*)g, (AS3 void*)l, 16, 0, 0);
}

// R9: softcap 50*tanh(s/50) without libm tanhf (libm chain is ~25-50 slow
// insts; no fast-math in harness flags).  tanh(|y|) = (1-e^{-2|y|})/(1+e^{-2|y|}),
// sign restored; e^{-2|y|} in (0,1] so no overflow for any s.  __expf ->
// v_exp_f32, rcp -> v_rcp_f32 (~1ulp; error *50 ~ 5e-6, negligible vs bf16).
__device__ __forceinline__ float softcap50(float s) {
  const float t  = __expf(-fabsf(s) * 0.04f);
  const float th = (1.f - t) * __builtin_amdgcn_rcpf(1.f + t);
  return copysignf(50.f * th, s);
}

// ---------------------------------------------------------------------------
// Weight cast+transpose: dst[n][k] = (bf16)src[k][n].  B^T layout so GEMM
// B-fragments are 8-contiguous-k b128 reads (layout proven by m92/m97).
// grid: (N/32, K/32), block (32,8)
// ---------------------------------------------------------------------------
__global__ void transpose_cast_kernel(const float* __restrict__ src, int ldsrc,
                                      bf16* __restrict__ dst, int lddst,
                                      int K, int N) {
  __shared__ float tile[32][33];
  const int n0 = blockIdx.x * 32, k0 = blockIdx.y * 32;
  const int tx = threadIdx.x, ty = threadIdx.y;
#pragma unroll
  for (int i = 0; i < 32; i += 8)
    tile[ty + i][tx] = src[(size_t)(k0 + ty + i) * ldsrc + n0 + tx];
  __syncthreads();
#pragma unroll
  for (int i = 0; i < 32; i += 8)
    dst[(size_t)(n0 + ty + i) * lddst + k0 + tx] = (bf16)tile[tx][ty + i];
}

// V transpose: vt[(b*KV+h)*D + d][t] = qkv[b*T+t][1536 + h*128 + d]
// grid: (T/32, D/32, B*KV), block (32,8)
__global__ void transpose_v_kernel(const bf16* __restrict__ qkv, bf16* __restrict__ vt) {
  __shared__ bf16 tile[32][33];
  const int bh = blockIdx.z, b = bh >> 2, h = bh & 3;
  const int t0 = blockIdx.x * 32, d0 = blockIdx.y * 32;
  const int tx = threadIdx.x, ty = threadIdx.y;
#pragma unroll
  for (int i = 0; i < 32; i += 8)
    tile[ty + i][tx] = qkv[(size_t)(b * T_ + t0 + ty + i) * 2048 + 1536 + h * 128 + d0 + tx];
  __syncthreads();
#pragma unroll
  for (int i = 0; i < 32; i += 8)
    vt[(size_t)((b * KV_ + h) * D_ + d0 + ty + i) * T_ + t0 + tx] = tile[tx][ty + i];
}

// ---------------------------------------------------------------------------
// RoPE sin/cos table: [T][64] each (the two D/2 halves share angles)
// ---------------------------------------------------------------------------
__global__ void rope_table_kernel(float* __restrict__ ct, float* __restrict__ st) {
  const int idx = blockIdx.x * 256 + threadIdx.x;
  if (idx >= T_ * 64) return;
  const int t = idx >> 6, i = idx & 63;
  const float inv = __expf(-(float)i * (1.0f / 64.0f) * logf(10000.0f));
  const float a = (float)t * inv;
  ct[idx] = cosf(a);
  st[idx] = sinf(a);
}

// ---------------------------------------------------------------------------
// RMSNorm (fp32 in) -> bf16 out.  One block per row, 256 threads * float4.
// ---------------------------------------------------------------------------
__global__ __launch_bounds__(256) void rmsnorm_kernel(const float* __restrict__ x,
                                                      const float* __restrict__ scale,
                                                      bf16* __restrict__ out) {
  const int row = blockIdx.x;
  const float* xr = x + (size_t)row * C_;
  const int tid = threadIdx.x;
  float4 v = ((const float4*)xr)[tid];
  float ss = v.x * v.x + v.y * v.y + v.z * v.z + v.w * v.w;
#pragma unroll
  for (int o = 32; o > 0; o >>= 1) ss += __shfl_down(ss, o);
  __shared__ float part[4];
  __shared__ float total;
  if ((tid & 63) == 0) part[tid >> 6] = ss;
  __syncthreads();
  if (tid == 0) total = part[0] + part[1] + part[2] + part[3];
  __syncthreads();
  const float r = rsqrtf(total * (1.0f / C_) + 1e-6f);
  float4 sc = ((const float4*)scale)[tid];
  bf16x4 o4;
  o4[0] = (bf16)(v.x * r * (1.f + sc.x));
  o4[1] = (bf16)(v.y * r * (1.f + sc.y));
  o4[2] = (bf16)(v.z * r * (1.f + sc.z));
  o4[3] = (bf16)(v.w * r * (1.f + sc.w));
  *(bf16x4*)(out + (size_t)row * C_ + tid * 4) = o4;
}

// ---------------------------------------------------------------------------
// RoPE apply + scatter into attention layouts.
// qkv row layout: cols [0,1024) q heads (hh = r*KV+h), [1024,1536) k, rest v.
// Qr[b][hh][t][d] (scaled by rsqrt(D)), Kr[b][h][t][d].  V handled separately.
// grid: NTOK blocks, 256 threads (4 waves x 3 head-chunks, lane = rope pair idx)
// ---------------------------------------------------------------------------
__global__ __launch_bounds__(256) void rope_apply_kernel(const bf16* __restrict__ qkv,
                                                         const float* __restrict__ ct,
                                                         const float* __restrict__ st,
                                                         bf16* __restrict__ Qr,
                                                         bf16* __restrict__ Kr) {
  const int row = blockIdx.x;            // b*T + t
  const int b = row >> 11, t = row & (T_ - 1);
  const int w = threadIdx.x >> 6, lane = threadIdx.x & 63;
  const float c = ct[t * 64 + lane], s = st[t * 64 + lane];
#pragma unroll
  for (int q = 0; q < 3; ++q) {
    const int ch = w * 3 + q;            // 0..11  (8 q-heads, 4 k-heads)
    const bf16* src = qkv + (size_t)row * 2048 + ch * 128;
    float x1 = (float)src[lane], x2 = (float)src[lane + 64];
    float o1 = x1 * c - x2 * s;
    float o2 = x2 * c + x1 * s;
    bf16* dst;
    if (ch < 8) {
      o1 *= QK_SCALE; o2 *= QK_SCALE;
      dst = Qr + (size_t)((b * H_ + ch) * T_ + t) * D_;
    } else {
      dst = Kr + (size_t)((b * KV_ + (ch - 8)) * T_ + t) * D_;
    }
    dst[lane] = (bf16)o1;
    dst[lane + 64] = (bf16)o2;
  }
}

// ---------------------------------------------------------------------------
// Flash attention, sliding window + causal + softcap(50).
// grid (T/64, H, B); 4 waves/block, each wave owns 16 q-rows independently
// (no barriers -- waves have different KV ranges).  KV tiles of 32.
// kv head = hh % KV (reference reshapes q_kernel to (C,R,KV,D): hh = r*KV+h).
// Pl rows padded to 40 elements (80B = 5x16B, so b128 reads stay aligned).
// Edge case (audited r3): whole-row-invalid first tile -> mnew==-inf no-op
// branch REQUIRED (prevents exp(-inf-(-inf))=NaN poisoning l_r).
// R9: tanhf -> softcap50 (exp-identity, ~4x fewer VALU ops on the softcap,
// which dominated the per-tile VALU bill); epilogue divide -> rcp once/row.
// [UNBENCHED r10: infra failure -- prediction: attn -15 to -25us, total
// 412 -> 385-400us, GEMM counters bit-identical, absmax 0.03125]
// ---------------------------------------------------------------------------
__global__ __launch_bounds__(256) void attn_kernel(const bf16* __restrict__ Qr,
                                                   const bf16* __restrict__ Kr,
                                                   const bf16* __restrict__ Vt,
                                                   bf16* __restrict__ attno) {
  __shared__ bf16 Pl[4][16][40];         // per-wave P tile (i x j'), padded
  const int qt = blockIdx.x, hh = blockIdx.y, b = blockIdx.z;
  const int h = hh & (KV_ - 1);
  const int w = threadIdx.x >> 6, lane = threadIdx.x & 63;
  const int lrow = lane & 15, lgrp = lane >> 4;
  const int qb = qt * 64 + w * 16;

  const bf16* Qb = Qr + ((size_t)(b * H_ + hh) * T_ + qb + lrow) * D_;
  const bf16* Kb = Kr + (size_t)(b * KV_ + h) * T_ * D_;
  const bf16* Vb = Vt + (size_t)(b * KV_ + h) * D_ * T_;

  bf16x8 aq[4];
#pragma unroll
  for (int dt = 0; dt < 4; ++dt)
    aq[dt] = *(const bf16x8*)(Qb + dt * 32 + lgrp * 8);

  const f32x4 fz = {0.f, 0.f, 0.f, 0.f};
  f32x4 o[8];
#pragma unroll
  for (int i = 0; i < 8; ++i) o[i] = fz;
  float m_r[4], l_r[4];
#pragma unroll
  for (int r = 0; r < 4; ++r) { m_r[r] = -__builtin_inff(); l_r[r] = 0.f; }

  int jlo = qb - (WIN_ - 1); if (jlo < 0) jlo = 0;
  for (int j0 = (jlo & ~31); j0 <= qb + 15; j0 += 32) {
    // S = Q K^T  (two 16x16 col-tiles)
    f32x4 sv0 = fz, sv1 = fz;
#pragma unroll
    for (int dt = 0; dt < 4; ++dt) {
      bf16x8 bk0 = *(const bf16x8*)(Kb + (size_t)(j0 + lrow) * D_ + dt * 32 + lgrp * 8);
      bf16x8 bk1 = *(const bf16x8*)(Kb + (size_t)(j0 + 16 + lrow) * D_ + dt * 32 + lgrp * 8);
      sv0 = __builtin_amdgcn_mfma_f32_16x16x32_bf16(aq[dt], bk0, sv0, 0, 0, 0);
      sv1 = __builtin_amdgcn_mfma_f32_16x16x32_bf16(aq[dt], bk1, sv1, 0, 0, 0);
    }
    // softcap + mask.  C/D layout: col = lane&15, row = (lane>>4)*4 + reg.
    float ca0[4], ca1[4];
    const int c0 = j0 + lrow, c1 = c0 + 16;
#pragma unroll
    for (int r = 0; r < 4; ++r) {
      const int i = qb + lgrp * 4 + r;
      float a0 = softcap50(sv0[r]);
      float a1 = softcap50(sv1[r]);
      ca0[r] = (c0 <= i && c0 >= i - (WIN_ - 1)) ? a0 : -__builtin_inff();
      ca1[r] = (c1 <= i && c1 >= i - (WIN_ - 1)) ? a1 : -__builtin_inff();
    }
    // online softmax (row-reduce across the 16 lanes of the lane-group)
    float alpha[4];
#pragma unroll
    for (int r = 0; r < 4; ++r) {
      float mx = fmaxf(ca0[r], ca1[r]);
#pragma unroll
      for (int d = 1; d < 16; d <<= 1) mx = fmaxf(mx, __shfl_xor(mx, d));
      const float mnew = fmaxf(m_r[r], mx);
      float p0, p1, al;
      if (mnew == -__builtin_inff()) {    // whole-row-invalid tile: no-op
        p0 = 0.f; p1 = 0.f; al = 1.f;
      } else {
        al = __expf(m_r[r] - mnew);       // exp(-inf)=0 on first valid tile
        p0 = __expf(ca0[r] - mnew);
        p1 = __expf(ca1[r] - mnew);
      }
      float rs = p0 + p1;
#pragma unroll
      for (int d = 1; d < 16; d <<= 1) rs += __shfl_xor(rs, d);
      m_r[r] = mnew;
      l_r[r] = l_r[r] * al + rs;
      alpha[r] = al;
      Pl[w][lgrp * 4 + r][lrow]      = (bf16)p0;
      Pl[w][lgrp * 4 + r][lrow + 16] = (bf16)p1;
    }
#pragma unroll
    for (int dt = 0; dt < 8; ++dt) {
      o[dt][0] *= alpha[0]; o[dt][1] *= alpha[1];
      o[dt][2] *= alpha[2]; o[dt][3] *= alpha[3];
    }
    // wave-local LDS fence (no __syncthreads: waves have divergent trip counts)
    asm volatile("s_waitcnt lgkmcnt(0)" ::: "memory");
    bf16x8 pa = *(const bf16x8*)(&Pl[w][lrow][lgrp * 8]);
#pragma unroll
    for (int dt = 0; dt < 8; ++dt) {
      bf16x8 bv = *(const bf16x8*)(Vb + (size_t)(dt * 16 + lrow) * T_ + j0 + lgrp * 8);
      o[dt] = __builtin_amdgcn_mfma_f32_16x16x32_bf16(pa, bv, o[dt], 0, 0, 0);
    }
  }
  // epilogue: concat layout [b*T + t][hh*D + d] -> GEMM-ready [4096][1024]
  float inv_l[4];
#pragma unroll
  for (int r = 0; r < 4; ++r) inv_l[r] = 1.f / l_r[r];   // 4 divides, not 32
#pragma unroll
  for (int dt = 0; dt < 8; ++dt)
#pragma unroll
    for (int r = 0; r < 4; ++r) {
      const int i = qb + lgrp * 4 + r;
      attno[(size_t)(b * T_ + i) * (H_ * D_) + hh * D_ + dt * 16 + lrow] =
          (bf16)(o[dt][r] * inv_l[r]);
    }
}

// ---------------------------------------------------------------------------
// bf16 GEMM, m97 structure + R8 both-sides XOR swizzle (rule #21 / m173):
// LDS dest stays linear (gload_lds requires it); the global SOURCE col chunk
// is pre-swizzled (lane&7)^(lane>>3) -- valid because every staged 8-row
// group is 8-row-aligned so row&7 == lane>>3 -- and the ds_read col applies
// the same XOR: chunk' = (kk*4+lgrp) ^ (row&7).  16 lanes then hit 8
// distinct 16B slots covering all 32 banks = 2 lanes/bank = free (m136).
// R9 RESULT: conflicts 2.5e7 -> 0.0, fused 117.7 -> 91.0us (total 450->412).
// The m252 "T2 null on 2-phase" verdict did NOT transfer to our shapes --
// conflicts were ~35% of wall and un-hidden.  Measure the regime, don't
// import the verdict.
// EPI: 0 = bf16 store; 1 = fp32 store + fp32 residual.
// ---------------------------------------------------------------------------
template <int EPI, int BM>
__global__ __launch_bounds__(256) void gemm_bt_kernel(
    const bf16* __restrict__ A, const bf16* __restrict__ Bt,
    int N, int K,
    bf16* __restrict__ outb, float* __restrict__ outf,
    const float* __restrict__ residf) {
  constexpr int MF = BM / 32;                    // m-frags per wave
  __shared__ bf16 sA[BM][64];
  __shared__ bf16 sB[128][64];
  const int bm = blockIdx.y, bn = blockIdx.x;
  const int tid = threadIdx.x, w = tid >> 6, lane = tid & 63;
  const int wr = w >> 1, wc = w & 1;
  const int lrow = lane & 15, lgrp = lane >> 4;
  const int swz = lrow & 7;                      // read-side XOR key (=row&7)

  const bf16* Ab = A + (size_t)(bm * BM) * K;
  const bf16* Bb = Bt + (size_t)(bn * 128) * K;

  const f32x4 fz = {0.f, 0.f, 0.f, 0.f};
  f32x4 acc[MF][4];
#pragma unroll
  for (int m = 0; m < MF; ++m)
#pragma unroll
    for (int n = 0; n < 4; ++n) acc[m][n] = fz;

  const int stg_row = lane >> 3;                 // 0..7 within a wave's 8 rows
  const int stg_col = ((lane & 7) ^ (lane >> 3)) * 8;  // inverse-swizzled src

  for (int k0 = 0; k0 < K; k0 += 64) {
    __syncthreads();                             // readers of prev tile done
#pragma unroll
    for (int c = 0; c < MF; ++c) {               // A: BM rows, 32 rows/pass
      const int r = c * 32 + w * 8;              // 8-row aligned (swizzle req)
      gload_lds16(Ab + (size_t)(r + stg_row) * K + k0 + stg_col, &sA[r][0]);
    }
#pragma unroll
    for (int c = 0; c < 4; ++c) {                // B: 128 rows
      const int r = c * 32 + w * 8;
      gload_lds16(Bb + (size_t)(r + stg_row) * K + k0 + stg_col, &sB[r][0]);
    }
    __syncthreads();                             // drains vmcnt(0) first
#pragma unroll
    for (int kk = 0; kk < 2; ++kk) {
      const int rc = ((kk * 4 + lgrp) ^ swz) * 8;  // swizzled read col
      bf16x8 af[MF], bfr[4];
#pragma unroll
      for (int m = 0; m < MF; ++m)
        af[m] = *(const bf16x8*)(&sA[wr * (BM / 2) + m * 16 + lrow][rc]);
#pragma unroll
      for (int n = 0; n < 4; ++n)
        bfr[n] = *(const bf16x8*)(&sB[wc * 64 + n * 16 + lrow][rc]);
#pragma unroll
      for (int m = 0; m < MF; ++m)
#pragma unroll
        for (int n = 0; n < 4; ++n)
          acc[m][n] = __builtin_amdgcn_mfma_f32_16x16x32_bf16(af[m], bfr[n], acc[m][n], 0, 0, 0);
    }
  }

#pragma unroll
  for (int m = 0; m < MF; ++m) {
    const int row0 = bm * BM + wr * (BM / 2) + m * 16 + lgrp * 4;
#pragma unroll
    for (int n = 0; n < 4; ++n) {
      const int col = bn * 128 + wc * 64 + n * 16 + lrow;
#pragma unroll
      for (int r = 0; r < 4; ++r) {
        const size_t idx = (size_t)(row0 + r) * N + col;
        const float v = acc[m][n][r];
        if (EPI == 0) {
          outb[idx] = (bf16)v;
        } else {
          outf[idx] = v + residf[idx];
        }
      }
    }
  }
}

// ---------------------------------------------------------------------------
// Fused gate+up GEMM with silu combine.  hmid = silu(h2@Wg) * (h2@Wu).
// R9: 91.0us, Mfma 30.7%, VALU 43%, conflicts 0 (swizzled), HBM 13%.
// 755 TF effective = 84% of the m97-structure ~900 TF ceiling; next step
// past this is the 8-phase schedule (deferred: new-sync-structure risk).
// Wgu layout: gate rows [0,4096), up rows [4096,8192), both [.][1024] B^T.
// ---------------------------------------------------------------------------
__global__ __launch_bounds__(256) void fused_gateup_kernel(
    const bf16* __restrict__ A,        // h2 [4096][1024]
    const bf16* __restrict__ Wgu,      // [8192][1024]
    bf16* __restrict__ hmid) {         // [4096][4096]
  __shared__ bf16 sA[128][64];
  __shared__ bf16 sBg[64][64];
  __shared__ bf16 sBu[64][64];
  const int bm = blockIdx.y, bn = blockIdx.x;   // bm 0..31, bn 0..63
  const int tid = threadIdx.x, w = tid >> 6, lane = tid & 63;
  const int wr = w >> 1, wc = w & 1;
  const int lrow = lane & 15, lgrp = lane >> 4;
  const int swz = lrow & 7;

  const bf16* Ab = A + (size_t)(bm * 128) * 1024;
  const bf16* Bg = Wgu + (size_t)(bn * 64) * 1024;
  const bf16* Bu = Wgu + (size_t)(4096 + bn * 64) * 1024;

  const f32x4 fz = {0.f, 0.f, 0.f, 0.f};
  f32x4 accg[4][2], accu[4][2];
#pragma unroll
  for (int m = 0; m < 4; ++m)
#pragma unroll
    for (int n = 0; n < 2; ++n) { accg[m][n] = fz; accu[m][n] = fz; }

  const int stg_row = lane >> 3;                 // 0..7
  const int stg_col = ((lane & 7) ^ (lane >> 3)) * 8;  // inverse-swizzled src

  for (int k0 = 0; k0 < 1024; k0 += 64) {
    __syncthreads();
#pragma unroll
    for (int c = 0; c < 4; ++c) {                // A: 128 rows
      const int r = c * 32 + w * 8;
      gload_lds16(Ab + (size_t)(r + stg_row) * 1024 + k0 + stg_col, &sA[r][0]);
    }
#pragma unroll
    for (int c = 0; c < 2; ++c) {                // Bg, Bu: 64 rows each
      const int r = c * 32 + w * 8;
      gload_lds16(Bg + (size_t)(r + stg_row) * 1024 + k0 + stg_col, &sBg[r][0]);
      gload_lds16(Bu + (size_t)(r + stg_row) * 1024 + k0 + stg_col, &sBu[r][0]);
    }
    __syncthreads();                             // drains vmcnt(0) first
#pragma unroll
    for (int kk = 0; kk < 2; ++kk) {
      const int rc = ((kk * 4 + lgrp) ^ swz) * 8;
      bf16x8 af[4], bg[2], bu[2];
#pragma unroll
      for (int m = 0; m < 4; ++m)
        af[m] = *(const bf16x8*)(&sA[wr * 64 + m * 16 + lrow][rc]);
#pragma unroll
      for (int n = 0; n < 2; ++n) {
        bg[n] = *(const bf16x8*)(&sBg[wc * 32 + n * 16 + lrow][rc]);
        bu[n] = *(const bf16x8*)(&sBu[wc * 32 + n * 16 + lrow][rc]);
      }
#pragma unroll
      for (int m = 0; m < 4; ++m)
#pragma unroll
        for (int n = 0; n < 2; ++n) {
          accg[m][n] = __builtin_amdgcn_mfma_f32_16x16x32_bf16(af[m], bg[n], accg[m][n], 0, 0, 0);
          accu[m][n] = __builtin_amdgcn_mfma_f32_16x16x32_bf16(af[m], bu[n], accu[m][n], 0, 0, 0);
        }
    }
  }

#pragma unroll
  for (int m = 0; m < 4; ++m) {
    const int row0 = bm * 128 + wr * 64 + m * 16 + lgrp * 4;
#pragma unroll
    for (int n = 0; n < 2; ++n) {
      const int col = bn * 64 + wc * 32 + n * 16 + lrow;
#pragma unroll
      for (int r = 0; r < 4; ++r) {
        const float g = accg[m][n][r];
        const float u = accu[m][n][r];
        const float sg = g / (1.f + __expf(-g));
        hmid[(size_t)(row0 + r) * HID_ + col] = (bf16)(sg * u);
      }
    }
  }
}

// ---------------------------------------------------------------------------
extern "C" void kernel_launch(void* const* d_in, const int* in_sizes, int n_in,
                              void* d_out, int out_size, void* d_ws, size_t ws_size,
                              hipStream_t stream) {
  const float* x      = (const float*)d_in[0];
  const float* qk_w   = (const float*)d_in[1];
  const float* kk_w   = (const float*)d_in[2];
  const float* vk_w   = (const float*)d_in[3];
  const float* ok_w   = (const float*)d_in[4];
  const float* ascale = (const float*)d_in[5];
  const float* mscale = (const float*)d_in[6];
  const float* gk_w   = (const float*)d_in[7];
  const float* uk_w   = (const float*)d_in[8];
  const float* dk_w   = (const float*)d_in[9];
  float* out = (float*)d_out;

  char* p = (char*)d_ws;
  auto alloc = [&](size_t bytes) {
    char* r = p;
    p += (bytes + 255) & ~(size_t)255;
    return r;
  };
  bf16*  Wqkv = (bf16*)alloc((size_t)2048 * 1024 * 2);   // [N=2048][K=1024] B^T
  bf16*  Wo   = (bf16*)alloc((size_t)1024 * 1024 * 2);   // [1024][1024]
  bf16*  Wgu  = (bf16*)alloc((size_t)8192 * 1024 * 2);   // gate rows 0..4095, up 4096..8191
  bf16*  Wdn  = (bf16*)alloc((size_t)1024 * 4096 * 2);   // [1024][4096]
  float* ct   = (float*)alloc((size_t)T_ * 64 * 4);
  float* st   = (float*)alloc((size_t)T_ * 64 * 4);
  bf16*  h1   = (bf16*)alloc((size_t)NTOK * C_ * 2);
  bf16*  qkv  = (bf16*)alloc((size_t)NTOK * 2048 * 2);
  bf16*  Qr   = (bf16*)alloc((size_t)B_ * H_ * T_ * D_ * 2);
  bf16*  Kr   = (bf16*)alloc((size_t)B_ * KV_ * T_ * D_ * 2);
  bf16*  Vt   = (bf16*)alloc((size_t)B_ * KV_ * T_ * D_ * 2);
  bf16*  attno= (bf16*)alloc((size_t)NTOK * 1024 * 2);
  float* x2   = (float*)alloc((size_t)NTOK * C_ * 4);
  bf16*  h2   = (bf16*)alloc((size_t)NTOK * C_ * 2);
  bf16*  hmid = (bf16*)alloc((size_t)NTOK * HID_ * 2);
  (void)ws_size; (void)in_sizes; (void)n_in; (void)out_size;

  const dim3 tb(32, 8);

  // RoPE table + weight cast/transpose (independent of activations)
  rope_table_kernel<<<dim3((T_ * 64 + 255) / 256), dim3(256), 0, stream>>>(ct, st);
  transpose_cast_kernel<<<dim3(32, 32), tb, 0, stream>>>(qk_w, 1024, Wqkv, 1024, 1024, 1024);
  transpose_cast_kernel<<<dim3(16, 32), tb, 0, stream>>>(kk_w, 512, Wqkv + (size_t)1024 * 1024, 1024, 1024, 512);
  transpose_cast_kernel<<<dim3(16, 32), tb, 0, stream>>>(vk_w, 512, Wqkv + (size_t)1536 * 1024, 1024, 1024, 512);
  transpose_cast_kernel<<<dim3(32, 32), tb, 0, stream>>>(ok_w, 1024, Wo, 1024, 1024, 1024);
  transpose_cast_kernel<<<dim3(128, 32), tb, 0, stream>>>(gk_w, 4096, Wgu, 1024, 1024, 4096);
  transpose_cast_kernel<<<dim3(128, 32), tb, 0, stream>>>(uk_w, 4096, Wgu + (size_t)4096 * 1024, 1024, 1024, 4096);
  transpose_cast_kernel<<<dim3(32, 128), tb, 0, stream>>>(dk_w, 1024, Wdn, 4096, 4096, 1024);

  // Attention branch
  rmsnorm_kernel<<<dim3(NTOK), dim3(256), 0, stream>>>(x, ascale, h1);
  gemm_bt_kernel<0, 128><<<dim3(16, 32), dim3(256), 0, stream>>>(h1, Wqkv, 2048, 1024, qkv, nullptr, nullptr);
  rope_apply_kernel<<<dim3(NTOK), dim3(256), 0, stream>>>(qkv, ct, st, Qr, Kr);
  transpose_v_kernel<<<dim3(64, 4, 8), tb, 0, stream>>>(qkv, Vt);
  attn_kernel<<<dim3(32, 8, 2), dim3(256), 0, stream>>>(Qr, Kr, Vt, attno);
  // out-proj: BM=64 -> grid (8,64)=512 blocks = 2 blocks/CU
  gemm_bt_kernel<1, 64><<<dim3(8, 64), dim3(256), 0, stream>>>(attno, Wo, 1024, 1024, nullptr, x2, x);

  // MLP branch
  rmsnorm_kernel<<<dim3(NTOK), dim3(256), 0, stream>>>(x2, mscale, h2);
  // fused gate+up with silu combine (replaces two GEMMs + gbuf round-trip)
  fused_gateup_kernel<<<dim3(64, 32), dim3(256), 0, stream>>>(h2, Wgu, hmid);
  // down: BM=64 -> grid (8,64)=512 blocks = 2 blocks/CU
  gemm_bt_kernel<1, 64><<<dim3(8, 64), dim3(256), 0, stream>>>(hmid, Wdn, 1024, 4096, nullptr, out, x2);
}